// Round 1
// baseline (1003.955 us; speedup 1.0000x reference)
//
#include <hip/hip_runtime.h>
#include <cstdint>

#define TB 256
static constexpr int NBH = 64;     // B*H
static constexpr int NN  = 4096;   // sequence
static constexpr int DD  = 64;     // head dim
static constexpr int MM  = 256;    // features
static constexpr float DATA_NORM = 0.35355339059327373f; // 64^-0.25
static constexpr float RATIO     = 0.0625f;              // 1/sqrt(256)
static constexpr float EPSK      = 1e-4f;

// LDS strides (floats). 68 keeps float4 alignment + conflict-free staging; 268 for E rows.
#define XT_S 68
#define E_S  268

// ---------------- K0: projT[d][m] = data_norm * proj[m][d] ----------------
__global__ void prep_proj(const float* __restrict__ proj, float* __restrict__ projT) {
  int t = threadIdx.x;
  int d = t & 63, mq = t >> 6;
  for (int it = 0; it < 64; ++it) {
    int m = it * 4 + mq;
    projT[d * MM + m] = DATA_NORM * proj[m * DD + d];
  }
}

// ---------------- K1: fused k-pass ----------------
// Per 64-row tile: xd = Xtile @ projT  (8x8 acc/thread), track global max(xd),
// E = exp(xd - diag), S1 += E^T @ Vtile (8x8 acc/thread), S2 += colsum(V).
__global__ __launch_bounds__(TB, 1) void k_pass(
    const float* __restrict__ kk, const float* __restrict__ vv,
    const float* __restrict__ projT, float* __restrict__ s1p,
    float* __restrict__ s2p, unsigned* __restrict__ kmaxp, int NC) {
  extern __shared__ float sm[];
  float* xt   = sm;                 // [64 d][68]
  float* vt   = xt + 64 * XT_S;     // [64 n][68]
  float* E    = vt + 64 * XT_S;     // [64 n][268]
  float* diag = E + 64 * E_S;       // [64]
  float* dscr = diag + 64;          // [256]
  float* redw = dscr + 256;         // [4]

  const int t = threadIdx.x;
  const int bid = blockIdx.x;
  const int bh = bid / NC, nc = bid % NC;
  const int rowsPB = NN / NC;
  const int ntiles = rowsPB >> 6;
  const float* kb = kk + (size_t)bh * NN * DD;
  const float* vb = vv + (size_t)bh * NN * DD;
  const int tr = t >> 5, tm = t & 31;
  const int m0 = tm * 8, r0 = tr * 8, e0 = tr * 8;
  const int ld_r = t >> 6, ld_d = t & 63;

  float s1[8][8];
#pragma unroll
  for (int i = 0; i < 8; ++i)
#pragma unroll
    for (int j = 0; j < 8; ++j) s1[i][j] = 0.f;
  float s2a = 0.f;
  float gmax = -3.0e38f;

  for (int tile = 0; tile < ntiles; ++tile) {
    const int n0 = nc * rowsPB + (tile << 6);
    // stage X (transposed [d][r]) and V ([n][e])
#pragma unroll
    for (int p = 0; p < 16; ++p) {
      int r = p * 4 + ld_r;
      xt[ld_d * XT_S + r] = kb[(size_t)(n0 + r) * DD + ld_d];
      vt[r * XT_S + ld_d] = vb[(size_t)(n0 + r) * DD + ld_d];
    }
    __syncthreads();
    { // diag partials: diag = (1/16) * sum x^2
      int rr = t & 63, c = t >> 6;
      float s = 0.f;
#pragma unroll
      for (int j = 0; j < 16; ++j) { float xv = xt[(c * 16 + j) * XT_S + rr]; s += xv * xv; }
      dscr[c * 64 + rr] = s;
    }
    __syncthreads();
    if (t < 64) diag[t] = 0.0625f * (dscr[t] + dscr[64 + t] + dscr[128 + t] + dscr[192 + t]);
    __syncthreads();

    // phase A: xd tile, acc[r][m]
    float acc[8][8];
#pragma unroll
    for (int i = 0; i < 8; ++i)
#pragma unroll
      for (int j = 0; j < 8; ++j) acc[i][j] = 0.f;
#pragma unroll 4
    for (int d = 0; d < DD; ++d) {
      float4 a0 = *(const float4*)&xt[d * XT_S + r0];
      float4 a1 = *(const float4*)&xt[d * XT_S + r0 + 4];
      float4 b0 = *(const float4*)&projT[d * MM + m0];
      float4 b1 = *(const float4*)&projT[d * MM + m0 + 4];
      float ar[8] = {a0.x, a0.y, a0.z, a0.w, a1.x, a1.y, a1.z, a1.w};
      float br[8] = {b0.x, b0.y, b0.z, b0.w, b1.x, b1.y, b1.z, b1.w};
#pragma unroll
      for (int i = 0; i < 8; ++i)
#pragma unroll
        for (int j = 0; j < 8; ++j) acc[i][j] = fmaf(ar[i], br[j], acc[i][j]);
    }
    // global-max track + E = exp(xd - diag)
#pragma unroll
    for (int i = 0; i < 8; ++i) {
      const int r = r0 + i;
      const float dg = diag[r];
      float ev[8];
#pragma unroll
      for (int j = 0; j < 8; ++j) { gmax = fmaxf(gmax, acc[i][j]); ev[j] = __expf(acc[i][j] - dg); }
      *(float4*)&E[r * E_S + m0]     = make_float4(ev[0], ev[1], ev[2], ev[3]);
      *(float4*)&E[r * E_S + m0 + 4] = make_float4(ev[4], ev[5], ev[6], ev[7]);
    }
    __syncthreads();
    if (t < 64) { // S2 partial: colsum of V tile
      float s = 0.f;
#pragma unroll
      for (int n = 0; n < 64; ++n) s += vt[n * XT_S + t];
      s2a += s;
    }
    // phase B: S1[m][e] += sum_n E[n][m] * V[n][e]
#pragma unroll 2
    for (int n = 0; n < 64; ++n) {
      float4 ea = *(const float4*)&E[n * E_S + m0];
      float4 eb = *(const float4*)&E[n * E_S + m0 + 4];
      float4 va = *(const float4*)&vt[n * XT_S + e0];
      float4 vb4 = *(const float4*)&vt[n * XT_S + e0 + 4];
      float er[8] = {ea.x, ea.y, ea.z, ea.w, eb.x, eb.y, eb.z, eb.w};
      float vr[8] = {va.x, va.y, va.z, va.w, vb4.x, vb4.y, vb4.z, vb4.w};
#pragma unroll
      for (int i = 0; i < 8; ++i)
#pragma unroll
        for (int j = 0; j < 8; ++j) s1[i][j] = fmaf(er[i], vr[j], s1[i][j]);
    }
    __syncthreads();
  }

  // write S1/S2 partials
  float* o = s1p + (size_t)bid * (MM * 64);
#pragma unroll
  for (int i = 0; i < 8; ++i) {
    *(float4*)&o[(m0 + i) * 64 + e0]     = make_float4(s1[i][0], s1[i][1], s1[i][2], s1[i][3]);
    *(float4*)&o[(m0 + i) * 64 + e0 + 4] = make_float4(s1[i][4], s1[i][5], s1[i][6], s1[i][7]);
  }
  if (t < 64) s2p[(size_t)bid * 64 + t] = s2a;
  // global max -> atomic (monotone float->uint key; exact, order-independent)
#pragma unroll
  for (int off = 32; off; off >>= 1) gmax = fmaxf(gmax, __shfl_xor(gmax, off));
  if ((t & 63) == 0) redw[t >> 6] = gmax;
  __syncthreads();
  if (t == 0) {
    float mm2 = fmaxf(fmaxf(redw[0], redw[1]), fmaxf(redw[2], redw[3]));
    unsigned b = __float_as_uint(mm2);
    unsigned key = (b & 0x80000000u) ? ~b : (b | 0x80000000u);
    atomicMax(kmaxp, key);
  }
}

// ---------------- K2: ctx = ratio*exp(-stab)*sum(S1) + ratio*eps*sum(S2) ----------------
__global__ void ctx_finalize(const float* __restrict__ s1p, const float* __restrict__ s2p,
                             const unsigned* __restrict__ kmaxp, float* __restrict__ ctx, int NC) {
  __shared__ float s2s[64];
  const int bh = blockIdx.x, t = threadIdx.x;
  unsigned key = *kmaxp;
  unsigned b = (key & 0x80000000u) ? (key & 0x7fffffffu) : ~key;
  float stab = __uint_as_float(b);
  float esc = RATIO * __expf(-stab);
  if (t < 64) {
    float s = 0.f;
    for (int nc = 0; nc < NC; ++nc) s += s2p[(size_t)(bh * NC + nc) * 64 + t];
    s2s[t] = RATIO * EPSK * s;
  }
  __syncthreads();
  for (int i = 0; i < 64; ++i) {
    int idx = i * 256 + t;
    float s = 0.f;
    for (int nc = 0; nc < NC; ++nc) s += s1p[(size_t)(bh * NC + nc) * (MM * 64) + idx];
    ctx[(size_t)bh * (MM * 64) + idx] = esc * s + s2s[idx & 63];
  }
}

// ---------------- K4: fused q-pass ----------------
// Per 64-row tile: xd, per-row max, E = exp(xd-diag-rowmax)+eps, out = ratio * E @ ctx.
__global__ __launch_bounds__(TB, 1) void q_pass(
    const float* __restrict__ qq, const float* __restrict__ projT,
    const float* __restrict__ ctx, float* __restrict__ outp, int NC2) {
  extern __shared__ float sm[];
  float* ctxl = sm;                  // [256 m][64 e]
  float* xt   = ctxl + MM * 64;      // [64 d][68]
  float* E    = xt + 64 * XT_S;      // [64 r][268]
  float* diag = E + 64 * E_S;        // [64]
  float* rmax = diag + 64;           // [64]
  float* dscr = rmax + 64;           // [256]

  const int t = threadIdx.x, bid = blockIdx.x;
  const int bh = bid / NC2, nc = bid % NC2;
  const int rowsPB = NN / NC2, ntiles = rowsPB >> 6;
  const float* qb = qq + (size_t)bh * NN * DD;
  const int tr = t >> 5, tm = t & 31;
  const int m0 = tm * 8, r0 = tr * 8;
  const int rB = (t >> 3) * 2, e0B = (t & 7) * 8;
  const int ld_r = t >> 6, ld_d = t & 63;

#pragma unroll
  for (int p = 0; p < 16; ++p) {
    int i4 = p * 256 + t;
    *(float4*)&ctxl[i4 * 4] = *(const float4*)&ctx[(size_t)bh * (MM * 64) + i4 * 4];
  }
  for (int tile = 0; tile < ntiles; ++tile) {
    const int n0 = nc * rowsPB + (tile << 6);
#pragma unroll
    for (int p = 0; p < 16; ++p) {
      int r = p * 4 + ld_r;
      xt[ld_d * XT_S + r] = qb[(size_t)(n0 + r) * DD + ld_d];
    }
    __syncthreads();
    {
      int rr = t & 63, c = t >> 6;
      float s = 0.f;
#pragma unroll
      for (int j = 0; j < 16; ++j) { float xv = xt[(c * 16 + j) * XT_S + rr]; s += xv * xv; }
      dscr[c * 64 + rr] = s;
    }
    __syncthreads();
    if (t < 64) diag[t] = 0.0625f * (dscr[t] + dscr[64 + t] + dscr[128 + t] + dscr[192 + t]);
    __syncthreads();

    float acc[8][8];
#pragma unroll
    for (int i = 0; i < 8; ++i)
#pragma unroll
      for (int j = 0; j < 8; ++j) acc[i][j] = 0.f;
#pragma unroll 4
    for (int d = 0; d < DD; ++d) {
      float4 a0 = *(const float4*)&xt[d * XT_S + r0];
      float4 a1 = *(const float4*)&xt[d * XT_S + r0 + 4];
      float4 b0 = *(const float4*)&projT[d * MM + m0];
      float4 b1 = *(const float4*)&projT[d * MM + m0 + 4];
      float ar[8] = {a0.x, a0.y, a0.z, a0.w, a1.x, a1.y, a1.z, a1.w};
      float br[8] = {b0.x, b0.y, b0.z, b0.w, b1.x, b1.y, b1.z, b1.w};
#pragma unroll
      for (int i = 0; i < 8; ++i)
#pragma unroll
        for (int j = 0; j < 8; ++j) acc[i][j] = fmaf(ar[i], br[j], acc[i][j]);
    }
    // row max across the 32 threads sharing each row group (lanes within a 32-half)
    float lm[8];
#pragma unroll
    for (int i = 0; i < 8; ++i) {
      float vmx = acc[i][0];
#pragma unroll
      for (int j = 1; j < 8; ++j) vmx = fmaxf(vmx, acc[i][j]);
      lm[i] = vmx;
    }
#pragma unroll
    for (int off = 16; off; off >>= 1)
#pragma unroll
      for (int i = 0; i < 8; ++i) lm[i] = fmaxf(lm[i], __shfl_xor(lm[i], off));
    if (tm == 0) {
#pragma unroll
      for (int i = 0; i < 8; ++i) rmax[r0 + i] = lm[i];
    }
    __syncthreads();
    // E = exp(xd - diag - rowmax) + eps
#pragma unroll
    for (int i = 0; i < 8; ++i) {
      int r = r0 + i;
      float dg = diag[r] + rmax[r];
      float ev[8];
#pragma unroll
      for (int j = 0; j < 8; ++j) ev[j] = __expf(acc[i][j] - dg) + EPSK;
      *(float4*)&E[r * E_S + m0]     = make_float4(ev[0], ev[1], ev[2], ev[3]);
      *(float4*)&E[r * E_S + m0 + 4] = make_float4(ev[4], ev[5], ev[6], ev[7]);
    }
    __syncthreads();
    // phase B: out[r][e] = ratio * sum_m E[r][m] * ctx[m][e]
    float a2[2][8];
#pragma unroll
    for (int j = 0; j < 8; ++j) { a2[0][j] = 0.f; a2[1][j] = 0.f; }
#pragma unroll 4
    for (int m = 0; m < MM; ++m) {
      float s0 = E[rB * E_S + m];
      float s1_ = E[(rB + 1) * E_S + m];
      float4 c0 = *(const float4*)&ctxl[m * 64 + e0B];
      float4 c1 = *(const float4*)&ctxl[m * 64 + e0B + 4];
      float cr[8] = {c0.x, c0.y, c0.z, c0.w, c1.x, c1.y, c1.z, c1.w};
#pragma unroll
      for (int j = 0; j < 8; ++j) {
        a2[0][j] = fmaf(s0, cr[j], a2[0][j]);
        a2[1][j] = fmaf(s1_, cr[j], a2[1][j]);
      }
    }
    float* ob = outp + (size_t)(bh * NN + n0) * DD;
#pragma unroll
    for (int rj = 0; rj < 2; ++rj) {
      *(float4*)&ob[(size_t)(rB + rj) * DD + e0B] =
          make_float4(RATIO * a2[rj][0], RATIO * a2[rj][1], RATIO * a2[rj][2], RATIO * a2[rj][3]);
      *(float4*)&ob[(size_t)(rB + rj) * DD + e0B + 4] =
          make_float4(RATIO * a2[rj][4], RATIO * a2[rj][5], RATIO * a2[rj][6], RATIO * a2[rj][7]);
    }
    __syncthreads();
  }
}

extern "C" void kernel_launch(void* const* d_in, const int* in_sizes, int n_in,
                              void* d_out, int out_size, void* d_ws, size_t ws_size,
                              hipStream_t stream) {
  (void)in_sizes; (void)n_in; (void)out_size;
  const float* q    = (const float*)d_in[0];
  const float* k    = (const float*)d_in[1];
  const float* v    = (const float*)d_in[2];
  const float* proj = (const float*)d_in[3];
  float* out = (float*)d_out;
  char* wsb = (char*)d_ws;

  // workspace layout: [kmax key(4B) pad to 256][projT 64KB][S1 partials][S2 partials][ctx]
  int NC = 8;
  auto need = [&](int nc) -> size_t {
    size_t off = 256 + 65536;
    off += (size_t)nc * NBH * MM * 64 * 4; // S1 partials
    off += (size_t)nc * NBH * 64 * 4;      // S2 partials
    off += (size_t)NBH * MM * 64 * 4;      // ctx
    return off;
  };
  while (NC > 1 && need(NC) > ws_size) NC >>= 1;

  unsigned* kmaxp = (unsigned*)wsb;
  float* projT = (float*)(wsb + 256);
  float* s1p = (float*)(wsb + 256 + 65536);
  float* s2p = (float*)((char*)s1p + (size_t)NC * NBH * MM * 64 * 4);
  float* ctx = (float*)((char*)s2p + (size_t)NC * NBH * 64 * 4);
  const int NC2 = 16;

  size_t lds1 = (size_t)(64 * XT_S * 2 + 64 * E_S + 64 + 256 + 4) * 4;           // ~104.7 KB
  size_t lds4 = (size_t)(MM * 64 + 64 * XT_S + 64 * E_S + 64 + 64 + 256) * 4;    // ~153.1 KB
  hipFuncSetAttribute((const void*)k_pass, hipFuncAttributeMaxDynamicSharedMemorySize, (int)lds1);
  hipFuncSetAttribute((const void*)q_pass, hipFuncAttributeMaxDynamicSharedMemorySize, (int)lds4);

  hipMemsetAsync(wsb, 0, 4, stream); // kmax key = 0 (== -inf under the monotone map)
  hipLaunchKernelGGL(prep_proj, dim3(1), dim3(TB), 0, stream, proj, projT);
  hipLaunchKernelGGL(k_pass, dim3(NBH * NC), dim3(TB), lds1, stream, k, v, projT, s1p, s2p, kmaxp, NC);
  hipLaunchKernelGGL(ctx_finalize, dim3(NBH), dim3(TB), 0, stream, s1p, s2p, kmaxp, ctx, NC);
  hipLaunchKernelGGL(q_pass, dim3(NBH * NC2), dim3(TB), lds4, stream, q, projT, ctx, out, NC2);
}

// Round 2
// 319.283 us; speedup vs baseline: 3.1444x; 3.1444x over previous
//
#include <hip/hip_runtime.h>
#include <cstdint>

typedef __bf16 bf16x8 __attribute__((ext_vector_type(8)));
typedef float f32x16 __attribute__((ext_vector_type(16)));

#define MFMA32(a, b, c) __builtin_amdgcn_mfma_f32_32x32x16_bf16(a, b, c, 0, 0, 0)

static constexpr int NBH = 64;     // B*H
static constexpr int NN  = 4096;
static constexpr int DD  = 64;
static constexpr int MM  = 256;
static constexpr float DATA_NORM = 0.35355339059327373f; // 64^-0.25
static constexpr float RATIO     = 0.0625f;              // 1/sqrt(256)
static constexpr float EPSK      = 1e-4f;

__device__ __forceinline__ unsigned short bf16rn(float f) {
  unsigned u = __float_as_uint(f);
  return (unsigned short)((u + 0x7FFFu + ((u >> 16) & 1u)) >> 16);
}
__device__ __forceinline__ float bf2f(unsigned short h) {
  return __uint_as_float(((unsigned)h) << 16);
}

// ---------------- prep: pa[combo=mt*4+kt][lane][8] = bf16(dn*proj), A-fragment packed ----------------
// A-frag (32x32x16): lane l holds row m = mt*32+(l&31), k(d) = kt*16 + 8*(l>>5) + j
__global__ void prep_proj(const float* __restrict__ proj, unsigned short* __restrict__ paU) {
  const int l = threadIdx.x, combo = blockIdx.x; // 32 blocks x 64 thr
  const int mt = combo >> 2, kt = combo & 3;
  const int m = mt * 32 + (l & 31);
  const int d0 = kt * 16 + 8 * (l >> 5);
  unsigned short pk[8];
#pragma unroll
  for (int j = 0; j < 8; ++j) pk[j] = bf16rn(DATA_NORM * proj[m * 64 + d0 + j]);
  uint4 u = make_uint4(pk[0] | ((unsigned)pk[1] << 16), pk[2] | ((unsigned)pk[3] << 16),
                       pk[4] | ((unsigned)pk[5] << 16), pk[6] | ((unsigned)pk[7] << 16));
  *(uint4*)(paU + (size_t)(combo * 64 + l) * 8) = u;
}

// ---------------- k_pass: xd^T = P·K^T (MFMA, hi/lo split), E=exp(xd-diag), S1 += E^T·V, gmax ----------------
__global__ __launch_bounds__(256, 2) void k_pass(
    const float* __restrict__ kk, const float* __restrict__ vv,
    const bf16x8* __restrict__ paG, float* __restrict__ s1p,
    float* __restrict__ s2p, unsigned* __restrict__ kmaxp, int NC) {
  extern __shared__ char smc[];
  constexpr int KH = 0, KL = 8192, VT = 16384, ET = 24576, DG = 57344, RD = 57600;
  const int t = threadIdx.x, l = t & 63, wv = t >> 6;
  const int bid = blockIdx.x, bh = bid / NC, nc = bid - bh * NC;
  const int rowsPB = NN / NC, ntiles = rowsPB >> 6;
  const float* kb = kk + (size_t)bh * NN * DD;
  const float* vb = vv + (size_t)bh * NN * DD;
  const int r = t >> 2, c0 = (t & 3) * 16;
  const int l31 = l & 31, lh = l >> 5;

  f32x16 accS[2][2];
#pragma unroll
  for (int a = 0; a < 2; ++a)
#pragma unroll
    for (int b = 0; b < 2; ++b)
#pragma unroll
      for (int i = 0; i < 16; ++i) accS[a][b][i] = 0.f;
  float s2loc[16];
#pragma unroll
  for (int j = 0; j < 16; ++j) s2loc[j] = 0.f;
  float gmax = -3.0e38f;

  for (int tile = 0; tile < ntiles; ++tile) {
    const int n0 = nc * rowsPB + (tile << 6);
    __syncthreads();
    // ---- stage K hi/lo (B-frag layout [n][d], swizzled) + V^T ([e][n]) + diag ----
    {
      const float* src = kb + (size_t)(n0 + r) * DD + c0;
      float x[16];
      *(float4*)&x[0]  = *(const float4*)(src + 0);
      *(float4*)&x[4]  = *(const float4*)(src + 4);
      *(float4*)&x[8]  = *(const float4*)(src + 8);
      *(float4*)&x[12] = *(const float4*)(src + 12);
      unsigned hp[8], lp[8];
      float ds = 0.f;
#pragma unroll
      for (int j = 0; j < 16; j += 2) {
        unsigned short ha = bf16rn(x[j]), hb = bf16rn(x[j + 1]);
        unsigned short la = bf16rn(x[j] - bf2f(ha)), lb = bf16rn(x[j + 1] - bf2f(hb));
        hp[j >> 1] = (unsigned)ha | ((unsigned)hb << 16);
        lp[j >> 1] = (unsigned)la | ((unsigned)lb << 16);
        ds += x[j] * x[j] + x[j + 1] * x[j + 1];
      }
      const int rowb = r * 128, sw = (r & 7) << 4;
      *(uint4*)(smc + KH + rowb + ((c0 * 2) ^ sw))      = make_uint4(hp[0], hp[1], hp[2], hp[3]);
      *(uint4*)(smc + KH + rowb + ((c0 * 2 + 16) ^ sw)) = make_uint4(hp[4], hp[5], hp[6], hp[7]);
      *(uint4*)(smc + KL + rowb + ((c0 * 2) ^ sw))      = make_uint4(lp[0], lp[1], lp[2], lp[3]);
      *(uint4*)(smc + KL + rowb + ((c0 * 2 + 16) ^ sw)) = make_uint4(lp[4], lp[5], lp[6], lp[7]);
      ds += __shfl_xor(ds, 1);
      ds += __shfl_xor(ds, 2);
      if ((t & 3) == 0) ((float*)(smc + DG))[r] = ds * 0.0625f; // 0.5*dn^2 = 1/16
      const float* vsrc = vb + (size_t)(n0 + r) * DD + c0;
      float w0[16];
      *(float4*)&w0[0]  = *(const float4*)(vsrc + 0);
      *(float4*)&w0[4]  = *(const float4*)(vsrc + 4);
      *(float4*)&w0[8]  = *(const float4*)(vsrc + 8);
      *(float4*)&w0[12] = *(const float4*)(vsrc + 12);
#pragma unroll
      for (int j = 0; j < 16; ++j) {
        int e = c0 + j;
        *(unsigned short*)(smc + VT + e * 128 + ((2 * r) ^ ((e & 7) << 4))) = bf16rn(w0[j]);
        s2loc[j] += w0[j];
      }
    }
    __syncthreads();
    // ---- phase A: acc[mt2][nt] = xd^T quadrant (row=m, col=n) ----
    f32x16 acc[2][2];
#pragma unroll
    for (int a = 0; a < 2; ++a)
#pragma unroll
      for (int b = 0; b < 2; ++b)
#pragma unroll
        for (int i = 0; i < 16; ++i) acc[a][b][i] = 0.f;
#pragma unroll
    for (int kt = 0; kt < 4; ++kt) {
      bf16x8 af0 = paG[((wv * 2 + 0) * 4 + kt) * 64 + l];
      bf16x8 af1 = paG[((wv * 2 + 1) * 4 + kt) * 64 + l];
      const int kb_ = kt * 32 + 16 * lh;
      const int nA = l31, nB = 32 + l31;
      const int swn = (nA & 7) << 4; // (nB&7)==(nA&7)
      bf16x8 bh0 = *(const bf16x8*)(smc + KH + nA * 128 + (kb_ ^ swn));
      bf16x8 bl0 = *(const bf16x8*)(smc + KL + nA * 128 + (kb_ ^ swn));
      bf16x8 bh1 = *(const bf16x8*)(smc + KH + nB * 128 + (kb_ ^ swn));
      bf16x8 bl1 = *(const bf16x8*)(smc + KL + nB * 128 + (kb_ ^ swn));
      acc[0][0] = MFMA32(af0, bh0, acc[0][0]); acc[0][0] = MFMA32(af0, bl0, acc[0][0]);
      acc[0][1] = MFMA32(af0, bh1, acc[0][1]); acc[0][1] = MFMA32(af0, bl1, acc[0][1]);
      acc[1][0] = MFMA32(af1, bh0, acc[1][0]); acc[1][0] = MFMA32(af1, bl0, acc[1][0]);
      acc[1][1] = MFMA32(af1, bh1, acc[1][1]); acc[1][1] = MFMA32(af1, bl1, acc[1][1]);
    }
    // ---- gmax + E^T = exp(xd - diag) -> LDS bf16 [m][n] ----
    {
      const float dv0 = ((const float*)(smc + DG))[l31];
      const float dv1 = ((const float*)(smc + DG))[32 + l31];
      const int n2a = 2 * l31, n2b = 2 * (32 + l31);
#pragma unroll
      for (int mt2 = 0; mt2 < 2; ++mt2) {
        const int mbase = (wv * 2 + mt2) * 32 + 4 * lh;
#pragma unroll
        for (int i = 0; i < 16; ++i) {
          const int m = mbase + (i & 3) + 8 * (i >> 2);
          const int sw2 = (m & 7) << 4;
          const float xv0 = acc[mt2][0][i], xv1 = acc[mt2][1][i];
          gmax = fmaxf(gmax, fmaxf(xv0, xv1));
          *(unsigned short*)(smc + ET + m * 128 + (n2a ^ sw2)) = bf16rn(__expf(xv0 - dv0));
          *(unsigned short*)(smc + ET + m * 128 + (n2b ^ sw2)) = bf16rn(__expf(xv1 - dv1));
        }
      }
    }
    __syncthreads();
    // ---- PV: S1[m][e] += E^T(A) · V^T-as-B ----
#pragma unroll
    for (int kt = 0; kt < 4; ++kt) {
      const int kb_ = kt * 32 + 16 * lh;
      const int mA = (wv * 2 + 0) * 32 + l31, mB = (wv * 2 + 1) * 32 + l31;
      const int swm = (mA & 7) << 4;
      bf16x8 a0 = *(const bf16x8*)(smc + ET + mA * 128 + (kb_ ^ swm));
      bf16x8 a1 = *(const bf16x8*)(smc + ET + mB * 128 + (kb_ ^ swm));
      const int eA = l31, eB = 32 + l31;
      const int swe = (eA & 7) << 4;
      bf16x8 b0 = *(const bf16x8*)(smc + VT + eA * 128 + (kb_ ^ swe));
      bf16x8 b1 = *(const bf16x8*)(smc + VT + eB * 128 + (kb_ ^ swe));
      accS[0][0] = MFMA32(a0, b0, accS[0][0]);
      accS[0][1] = MFMA32(a0, b1, accS[0][1]);
      accS[1][0] = MFMA32(a1, b0, accS[1][0]);
      accS[1][1] = MFMA32(a1, b1, accS[1][1]);
    }
  }
  // ---- write S1 partials ----
  {
    float* o = s1p + (size_t)bid * (MM * 64);
#pragma unroll
    for (int mt2 = 0; mt2 < 2; ++mt2)
#pragma unroll
      for (int et = 0; et < 2; ++et)
#pragma unroll
        for (int i = 0; i < 16; ++i) {
          const int m = (wv * 2 + mt2) * 32 + 4 * lh + (i & 3) + 8 * (i >> 2);
          const int e = et * 32 + l31;
          o[m * 64 + e] = accS[mt2][et][i];
        }
  }
  // ---- S2 reduce (reuse ET region as scratch) ----
  __syncthreads();
  {
    float* scr = (float*)(smc + ET);
#pragma unroll
    for (int j = 0; j < 16; ++j) scr[t * 16 + j] = s2loc[j];
    __syncthreads();
    if (t < 64) {
      float s = 0.f;
      for (int q2 = 0; q2 < 64; ++q2) s += scr[(q2 * 4 + (t >> 4)) * 16 + (t & 15)];
      s2p[(size_t)bid * 64 + t] = s;
    }
  }
  // ---- global max ----
#pragma unroll
  for (int off = 32; off; off >>= 1) gmax = fmaxf(gmax, __shfl_xor(gmax, off));
  if (l == 0) ((float*)(smc + RD))[wv] = gmax;
  __syncthreads();
  if (t == 0) {
    float* rd = (float*)(smc + RD);
    float m4 = fmaxf(fmaxf(rd[0], rd[1]), fmaxf(rd[2], rd[3]));
    unsigned b = __float_as_uint(m4);
    unsigned key = (b & 0x80000000u) ? ~b : (b | 0x80000000u);
    atomicMax(kmaxp, key);
  }
}

// ---------------- ctx_finalize: ctx = ratio*(e^-stab*S1 + eps*S2); pack cb (B-frag), epst ----------------
__global__ void ctx_finalize(const float* __restrict__ s1p, const float* __restrict__ s2p,
                             const unsigned* __restrict__ kmaxp, unsigned short* __restrict__ cbU,
                             float* __restrict__ epstG, int NC) {
  extern __shared__ char smc[];
  float* ctxl = (float*)smc;             // [256][64] fp32 = 64KB
  float* s2s  = (float*)(smc + 65536);   // [64]
  float* csr  = (float*)(smc + 65792);   // [4][64]
  const int t = threadIdx.x, bh = blockIdx.x;
  const unsigned key = *kmaxp;
  const unsigned b = (key & 0x80000000u) ? (key & 0x7fffffffu) : ~key;
  const float stab = __uint_as_float(b);
  const float esc = RATIO * __expf(-stab);
  if (t < 64) {
    float s = 0.f;
    for (int nc = 0; nc < NC; ++nc) s += s2p[(size_t)(bh * NC + nc) * 64 + t];
    s2s[t] = RATIO * EPSK * s;
  }
  __syncthreads();
  const int e = t & 63, w = t >> 6;
  float cs = 0.f;
  for (int i = 0; i < 64; ++i) {
    const int m = i * 4 + w;
    const int idx = m * 64 + e;
    float s = 0.f;
    for (int nc = 0; nc < NC; ++nc) s += s1p[(size_t)(bh * NC + nc) * 16384 + idx];
    const float val = esc * s + s2s[e];
    ctxl[idx] = val;
    cs += val;
  }
  csr[w * 64 + e] = cs;
  __syncthreads();
  if (t < 64)
    epstG[bh * 64 + t] = RATIO * EPSK * (csr[t] + csr[64 + t] + csr[128 + t] + csr[192 + t]);
  // pack cb: B-frag for q-PV: lane l: col e=et*32+(l&31), k(m)=kt*16+8*(l>>5)+j
  const int l = t & 63;
  unsigned short* cbB = cbU + (size_t)bh * 16384;
  for (int it = 0; it < 8; ++it) {
    const int combo = it * 4 + w;       // = kt*2+et
    const int kt = combo >> 1, et = combo & 1;
    unsigned short pk[8];
#pragma unroll
    for (int j = 0; j < 8; ++j) {
      const int m = kt * 16 + 8 * (l >> 5) + j;
      const int e2 = et * 32 + (l & 31);
      pk[j] = bf16rn(ctxl[m * 64 + e2]);
    }
    uint4 u = make_uint4(pk[0] | ((unsigned)pk[1] << 16), pk[2] | ((unsigned)pk[3] << 16),
                         pk[4] | ((unsigned)pk[5] << 16), pk[6] | ((unsigned)pk[7] << 16));
    *(uint4*)(cbB + (size_t)(combo * 64 + l) * 8) = u;
  }
}

// ---------------- q_pass: xd^T, per-row max, Eq=exp(xd-diag-rmax), out = ratio*Eq·ctx + epst ----------------
__global__ __launch_bounds__(256, 2) void q_pass(
    const float* __restrict__ qq, const bf16x8* __restrict__ paG,
    const bf16x8* __restrict__ cbG, const float* __restrict__ epstG,
    float* __restrict__ outp, int NC2) {
  extern __shared__ char smc[];
  constexpr int QH = 0, QL = 8192, EQ = 16384, DG = 49152, WQ = 49408;
  const int t = threadIdx.x, l = t & 63, wv = t >> 6;
  const int bid = blockIdx.x, bh = bid / NC2, nc = bid - bh * NC2;
  const int rowsPB = NN / NC2, ntiles = rowsPB >> 6;
  const float* qb = qq + (size_t)bh * NN * DD;
  float* ob = outp + (size_t)bh * NN * DD;
  const int r = t >> 2, c0 = (t & 3) * 16;
  const int l31 = l & 31, lh = l >> 5;
  const int pnt = wv & 1, pet = wv >> 1;
  const bf16x8* cbB = cbG + (size_t)bh * 2048;
  const float ept = epstG[bh * 64 + pet * 32 + l31];

  for (int tile = 0; tile < ntiles; ++tile) {
    const int n0 = nc * rowsPB + (tile << 6);
    __syncthreads();
    // ---- stage Q hi/lo + diag ----
    {
      const float* src = qb + (size_t)(n0 + r) * DD + c0;
      float x[16];
      *(float4*)&x[0]  = *(const float4*)(src + 0);
      *(float4*)&x[4]  = *(const float4*)(src + 4);
      *(float4*)&x[8]  = *(const float4*)(src + 8);
      *(float4*)&x[12] = *(const float4*)(src + 12);
      unsigned hp[8], lp[8];
      float ds = 0.f;
#pragma unroll
      for (int j = 0; j < 16; j += 2) {
        unsigned short ha = bf16rn(x[j]), hb = bf16rn(x[j + 1]);
        unsigned short la = bf16rn(x[j] - bf2f(ha)), lb = bf16rn(x[j + 1] - bf2f(hb));
        hp[j >> 1] = (unsigned)ha | ((unsigned)hb << 16);
        lp[j >> 1] = (unsigned)la | ((unsigned)lb << 16);
        ds += x[j] * x[j] + x[j + 1] * x[j + 1];
      }
      const int rowb = r * 128, sw = (r & 7) << 4;
      *(uint4*)(smc + QH + rowb + ((c0 * 2) ^ sw))      = make_uint4(hp[0], hp[1], hp[2], hp[3]);
      *(uint4*)(smc + QH + rowb + ((c0 * 2 + 16) ^ sw)) = make_uint4(hp[4], hp[5], hp[6], hp[7]);
      *(uint4*)(smc + QL + rowb + ((c0 * 2) ^ sw))      = make_uint4(lp[0], lp[1], lp[2], lp[3]);
      *(uint4*)(smc + QL + rowb + ((c0 * 2 + 16) ^ sw)) = make_uint4(lp[4], lp[5], lp[6], lp[7]);
      ds += __shfl_xor(ds, 1);
      ds += __shfl_xor(ds, 2);
      if ((t & 3) == 0) ((float*)(smc + DG))[r] = ds * 0.0625f;
    }
    __syncthreads();
    // ---- phase A ----
    f32x16 acc[2][2];
#pragma unroll
    for (int a = 0; a < 2; ++a)
#pragma unroll
      for (int b = 0; b < 2; ++b)
#pragma unroll
        for (int i = 0; i < 16; ++i) acc[a][b][i] = 0.f;
#pragma unroll
    for (int kt = 0; kt < 4; ++kt) {
      bf16x8 af0 = paG[((wv * 2 + 0) * 4 + kt) * 64 + l];
      bf16x8 af1 = paG[((wv * 2 + 1) * 4 + kt) * 64 + l];
      const int kb_ = kt * 32 + 16 * lh;
      const int nA = l31, nB = 32 + l31;
      const int swn = (nA & 7) << 4;
      bf16x8 bh0 = *(const bf16x8*)(smc + QH + nA * 128 + (kb_ ^ swn));
      bf16x8 bl0 = *(const bf16x8*)(smc + QL + nA * 128 + (kb_ ^ swn));
      bf16x8 bh1 = *(const bf16x8*)(smc + QH + nB * 128 + (kb_ ^ swn));
      bf16x8 bl1 = *(const bf16x8*)(smc + QL + nB * 128 + (kb_ ^ swn));
      acc[0][0] = MFMA32(af0, bh0, acc[0][0]); acc[0][0] = MFMA32(af0, bl0, acc[0][0]);
      acc[0][1] = MFMA32(af0, bh1, acc[0][1]); acc[0][1] = MFMA32(af0, bl1, acc[0][1]);
      acc[1][0] = MFMA32(af1, bh0, acc[1][0]); acc[1][0] = MFMA32(af1, bl0, acc[1][0]);
      acc[1][1] = MFMA32(af1, bh1, acc[1][1]); acc[1][1] = MFMA32(af1, bl1, acc[1][1]);
    }
    // ---- per-row (per-n) max over all m: wave-partial then cross-wave via LDS ----
    {
      float pm0 = -3.0e38f, pm1 = -3.0e38f;
#pragma unroll
      for (int mt2 = 0; mt2 < 2; ++mt2)
#pragma unroll
        for (int i = 0; i < 16; ++i) {
          pm0 = fmaxf(pm0, acc[mt2][0][i]);
          pm1 = fmaxf(pm1, acc[mt2][1][i]);
        }
      pm0 = fmaxf(pm0, __shfl_xor(pm0, 32));
      pm1 = fmaxf(pm1, __shfl_xor(pm1, 32));
      if (l < 32) {
        ((float*)(smc + WQ))[wv * 64 + l] = pm0;
        ((float*)(smc + WQ))[wv * 64 + 32 + l] = pm1;
      }
    }
    __syncthreads();
    {
      const float* wq = (const float*)(smc + WQ);
      const float rm0 = fmaxf(fmaxf(wq[l31], wq[64 + l31]), fmaxf(wq[128 + l31], wq[192 + l31]));
      const float rm1 = fmaxf(fmaxf(wq[32 + l31], wq[96 + l31]), fmaxf(wq[160 + l31], wq[224 + l31]));
      const float dv0 = ((const float*)(smc + DG))[l31] + rm0;
      const float dv1 = ((const float*)(smc + DG))[32 + l31] + rm1;
      // Eq -> LDS [n][m] bf16 (A-frag layout for PV), packed-pair b32 writes
      const int swa = (l31 & 7) << 4;
#pragma unroll
      for (int mt2 = 0; mt2 < 2; ++mt2) {
        const int mbase = (wv * 2 + mt2) * 32 + 4 * lh;
#pragma unroll
        for (int i = 0; i < 16; i += 2) {
          const int m = mbase + (i & 3) + 8 * (i >> 2);
          unsigned short e0 = bf16rn(__expf(acc[mt2][0][i] - dv0));
          unsigned short e1 = bf16rn(__expf(acc[mt2][0][i + 1] - dv0));
          *(unsigned*)(smc + EQ + l31 * 512 + ((2 * m) ^ swa)) = (unsigned)e0 | ((unsigned)e1 << 16);
          unsigned short f0 = bf16rn(__expf(acc[mt2][1][i] - dv1));
          unsigned short f1 = bf16rn(__expf(acc[mt2][1][i + 1] - dv1));
          *(unsigned*)(smc + EQ + (32 + l31) * 512 + ((2 * m) ^ swa)) = (unsigned)f0 | ((unsigned)f1 << 16);
        }
      }
    }
    __syncthreads();
    // ---- PV: out subtile (pnt, pet), K=256 over m, 2-acc ILP, 1-deep cb prefetch ----
    {
      f32x16 p0, p1;
#pragma unroll
      for (int i = 0; i < 16; ++i) { p0[i] = 0.f; p1[i] = 0.f; }
      const int n = pnt * 32 + l31;
      const int swn = (n & 7) << 4;
      bf16x8 bcur = cbB[(0 * 2 + pet) * 64 + l];
#pragma unroll
      for (int kt = 0; kt < 16; ++kt) {
        bf16x8 bnx = bcur;
        if (kt < 15) bnx = cbB[((kt + 1) * 2 + pet) * 64 + l];
        bf16x8 af = *(const bf16x8*)(smc + EQ + n * 512 + ((kt * 32 + 16 * lh) ^ swn));
        if (kt & 1) p1 = MFMA32(af, bcur, p1);
        else        p0 = MFMA32(af, bcur, p0);
        bcur = bnx;
      }
#pragma unroll
      for (int i = 0; i < 16; ++i) {
        const int nn = pnt * 32 + 4 * lh + (i & 3) + 8 * (i >> 2);
        const int e = pet * 32 + l31;
        ob[(size_t)(n0 + nn) * 64 + e] = RATIO * (p0[i] + p1[i]) + ept;
      }
    }
  }
}

extern "C" void kernel_launch(void* const* d_in, const int* in_sizes, int n_in,
                              void* d_out, int out_size, void* d_ws, size_t ws_size,
                              hipStream_t stream) {
  (void)in_sizes; (void)n_in; (void)out_size;
  const float* q    = (const float*)d_in[0];
  const float* k    = (const float*)d_in[1];
  const float* v    = (const float*)d_in[2];
  const float* proj = (const float*)d_in[3];
  float* out = (float*)d_out;
  char* wsb = (char*)d_ws;

  int NC = 8;
  auto need = [&](int nc) -> size_t {
    size_t off = 256 + 32768;                  // key + pa
    off += (size_t)nc * NBH * MM * 64 * 4;     // S1 partials
    off += (size_t)nc * NBH * 64 * 4;          // S2 partials
    off += (size_t)NBH * MM * 64 * 2;          // cb (bf16)
    off += (size_t)NBH * 64 * 4;               // epst
    return off;
  };
  while (NC > 1 && need(NC) > ws_size) NC >>= 1;

  unsigned* kmaxp = (unsigned*)wsb;
  bf16x8* paG = (bf16x8*)(wsb + 256);
  float* s1p = (float*)(wsb + 256 + 32768);
  float* s2p = (float*)((char*)s1p + (size_t)NC * NBH * MM * 64 * 4);
  unsigned short* cbU = (unsigned short*)((char*)s2p + (size_t)NC * NBH * 64 * 4);
  float* epstG = (float*)((char*)cbU + (size_t)NBH * MM * 64 * 2);
  const int NC2 = 16;

  const size_t lds_k = 57664, lds_q = 50432, lds_c = 66816;
  hipFuncSetAttribute((const void*)k_pass, hipFuncAttributeMaxDynamicSharedMemorySize, (int)lds_k);
  hipFuncSetAttribute((const void*)q_pass, hipFuncAttributeMaxDynamicSharedMemorySize, (int)lds_q);
  hipFuncSetAttribute((const void*)ctx_finalize, hipFuncAttributeMaxDynamicSharedMemorySize, (int)lds_c);

  hipMemsetAsync(wsb, 0, 4, stream);
  hipLaunchKernelGGL(prep_proj, dim3(32), dim3(64), 0, stream, proj, (unsigned short*)paG);
  hipLaunchKernelGGL(k_pass, dim3(NBH * NC), dim3(256), lds_k, stream, k, v, paG, s1p, s2p, kmaxp, NC);
  hipLaunchKernelGGL(ctx_finalize, dim3(NBH), dim3(256), lds_c, stream, s1p, s2p, kmaxp, cbU, epstG, NC);
  hipLaunchKernelGGL(q_pass, dim3(NBH * NC2), dim3(256), lds_q, stream, q, paG, (const bf16x8*)cbU, epstG, out, NC2);
}

// Round 3
// 298.646 us; speedup vs baseline: 3.3617x; 1.0691x over previous
//
#include <hip/hip_runtime.h>
#include <cstdint>

typedef __bf16 bf16x8 __attribute__((ext_vector_type(8)));
typedef float f32x16 __attribute__((ext_vector_type(16)));

#define MFMA32(a, b, c) __builtin_amdgcn_mfma_f32_32x32x16_bf16(a, b, c, 0, 0, 0)

static constexpr int NBH = 64;     // B*H
static constexpr int NN  = 4096;
static constexpr int DD  = 64;
static constexpr int MM  = 256;
static constexpr float DATA_NORM = 0.35355339059327373f; // 64^-0.25
static constexpr float RATIO     = 0.0625f;              // 1/sqrt(256)
static constexpr float EPSK      = 1e-4f;

__device__ __forceinline__ unsigned short bfu(float f) {
  return __builtin_bit_cast(unsigned short, (__bf16)f);
}
__device__ __forceinline__ unsigned pk2(float a, float b) {
  return (unsigned)bfu(a) | ((unsigned)bfu(b) << 16);
}
// hi/lo split-pack of 8 floats -> two uint4 (bf16 hi, bf16 residual lo)
__device__ __forceinline__ void pack_hilo8(const float* x, uint4& H, uint4& L) {
  unsigned h[4], lo[4];
#pragma unroll
  for (int p = 0; p < 4; ++p) {
    float a = x[2 * p], b = x[2 * p + 1];
    __bf16 ha = (__bf16)a, hb = (__bf16)b;
    float fa = (float)ha, fb = (float)hb;
    __bf16 la = (__bf16)(a - fa), lb = (__bf16)(b - fb);
    h[p]  = (unsigned)__builtin_bit_cast(unsigned short, ha) |
            ((unsigned)__builtin_bit_cast(unsigned short, hb) << 16);
    lo[p] = (unsigned)__builtin_bit_cast(unsigned short, la) |
            ((unsigned)__builtin_bit_cast(unsigned short, lb) << 16);
  }
  H = make_uint4(h[0], h[1], h[2], h[3]);
  L = make_uint4(lo[0], lo[1], lo[2], lo[3]);
}
__device__ __forceinline__ int swzV(int e) { return ((e & 7) << 4) ^ ((e & 8) << 1); }

// ---------------- prep: frag-packed proj (layout serves as both A-frag and B-frag) ----------------
// combo = mt*4+kt: lane l holds m = mt*32+(l&31), d = kt*16 + 8*(l>>5) + j
__global__ void prep_proj(const float* __restrict__ proj, unsigned short* __restrict__ paU) {
  const int l = threadIdx.x, combo = blockIdx.x; // 32 blocks x 64 thr
  const int mt = combo >> 2, kt = combo & 3;
  const int m = mt * 32 + (l & 31);
  const int d0 = kt * 16 + 8 * (l >> 5);
  unsigned short pk[8];
#pragma unroll
  for (int j = 0; j < 8; ++j) pk[j] = bfu(DATA_NORM * proj[m * 64 + d0 + j]);
  uint4 u = make_uint4(pk[0] | ((unsigned)pk[1] << 16), pk[2] | ((unsigned)pk[3] << 16),
                       pk[4] | ((unsigned)pk[5] << 16), pk[6] | ((unsigned)pk[7] << 16));
  *(uint4*)(paU + (size_t)(combo * 64 + l) * 8) = u;
}

// ---------------- k_pass: xd = K·P^T via MFMA (A=K rows n, B=proj cols m); E in-register;
//                  PV A-frags assembled via half-swap shfl; S1 += E^T·V; global max ----------------
__global__ __launch_bounds__(512, 4) void k_pass(
    const float* __restrict__ kk, const float* __restrict__ vv,
    const bf16x8* __restrict__ paG, float* __restrict__ s1p,
    float* __restrict__ s2p, unsigned* __restrict__ kmaxp, int NC) {
  extern __shared__ char smc[];
  constexpr int KH = 0, KL = 8192, VT = 16384, DG = 24576, RD = 24832;
  const int t = threadIdx.x, l = t & 63, wv = t >> 6;
  const int l31 = l & 31, lh = l >> 5;
  const int bid = blockIdx.x, bh = bid / NC, nc = bid - bh * NC;
  const int rowsPB = NN / NC, ntiles = rowsPB >> 6;
  const float* kb = kk + (size_t)bh * NN * DD;
  const float* vb = vv + (size_t)bh * NN * DD;
  const int r = t >> 3, cg = t & 7, c0 = cg * 8;
  const int swr = (r & 7) << 4;

  // proj B-frags for this wave's m-range (persistent regs)
  bf16x8 pb[4];
#pragma unroll
  for (int kt = 0; kt < 4; ++kt) pb[kt] = paG[(wv * 4 + kt) * 64 + l];

  f32x16 accS[2];
#pragma unroll
  for (int et = 0; et < 2; ++et)
#pragma unroll
    for (int i = 0; i < 16; ++i) accS[et][i] = 0.f;
  float s2loc[8];
#pragma unroll
  for (int j = 0; j < 8; ++j) s2loc[j] = 0.f;
  float gmax = -3.0e38f;

  float kx[8], vx[8];
  {
    const float* s = kb + (size_t)(nc * rowsPB + r) * DD + c0;
    *(float4*)&kx[0] = *(const float4*)(s + 0);
    *(float4*)&kx[4] = *(const float4*)(s + 4);
    const float* s2 = vb + (size_t)(nc * rowsPB + r) * DD + c0;
    *(float4*)&vx[0] = *(const float4*)(s2 + 0);
    *(float4*)&vx[4] = *(const float4*)(s2 + 4);
  }

  for (int tile = 0; tile < ntiles; ++tile) {
    // ---- stage K hi/lo ([n][d] A-frag layout) + V^T ([e][n]) + diag ----
    {
      uint4 H, L;
      pack_hilo8(kx, H, L);
      *(uint4*)(smc + KH + r * 128 + ((2 * c0) ^ swr)) = H;
      *(uint4*)(smc + KL + r * 128 + ((2 * c0) ^ swr)) = L;
      float ds = 0.f;
#pragma unroll
      for (int j = 0; j < 8; ++j) ds += kx[j] * kx[j];
      ds += __shfl_xor(ds, 1);
      ds += __shfl_xor(ds, 2);
      ds += __shfl_xor(ds, 4);
      if (cg == 0) ((float*)(smc + DG))[r] = ds * 0.0625f; // 0.5*dn^2 = 1/16
#pragma unroll
      for (int j = 0; j < 8; ++j) {
        const int e = c0 + j;
        *(unsigned short*)(smc + VT + e * 128 + ((2 * r) ^ swzV(e))) = bfu(vx[j]);
        s2loc[j] += vx[j];
      }
    }
    __syncthreads();
    // ---- prefetch next tile into regs (lands during compute) ----
    float kn[8], vn[8];
    if (tile + 1 < ntiles) {
      const float* s = kb + (size_t)(nc * rowsPB + (tile + 1) * 64 + r) * DD + c0;
      *(float4*)&kn[0] = *(const float4*)(s + 0);
      *(float4*)&kn[4] = *(const float4*)(s + 4);
      const float* s2 = vb + (size_t)(nc * rowsPB + (tile + 1) * 64 + r) * DD + c0;
      *(float4*)&vn[0] = *(const float4*)(s2 + 0);
      *(float4*)&vn[4] = *(const float4*)(s2 + 4);
    }
    // ---- phase A: acc[nt] = xd quadrants (row n in regs, col m = lane) ----
    f32x16 acc[2];
#pragma unroll
    for (int nt = 0; nt < 2; ++nt)
#pragma unroll
      for (int i = 0; i < 16; ++i) acc[nt][i] = 0.f;
    const int swa = (l31 & 7) << 4;
#pragma unroll
    for (int kt = 0; kt < 4; ++kt) {
      const int ko = kt * 32 + 16 * lh;
      bf16x8 ah0 = *(const bf16x8*)(smc + KH + l31 * 128 + (ko ^ swa));
      bf16x8 al0 = *(const bf16x8*)(smc + KL + l31 * 128 + (ko ^ swa));
      bf16x8 ah1 = *(const bf16x8*)(smc + KH + (32 + l31) * 128 + (ko ^ swa));
      bf16x8 al1 = *(const bf16x8*)(smc + KL + (32 + l31) * 128 + (ko ^ swa));
      acc[0] = MFMA32(ah0, pb[kt], acc[0]);
      acc[0] = MFMA32(al0, pb[kt], acc[0]);
      acc[1] = MFMA32(ah1, pb[kt], acc[1]);
      acc[1] = MFMA32(al1, pb[kt], acc[1]);
    }
#pragma unroll
    for (int nt = 0; nt < 2; ++nt)
#pragma unroll
      for (int i = 0; i < 16; ++i) gmax = fmaxf(gmax, acc[nt][i]);
    // ---- per-kt2: exp -> pack -> half-swap -> PV MFMA ----
    const float* dg = (const float*)(smc + DG);
#pragma unroll
    for (int kt2 = 0; kt2 < 4; ++kt2) {
      const int nt = kt2 >> 1, gb = (kt2 & 1) * 2;
      float eA[4], eB[4];
#pragma unroll
      for (int c = 0; c < 4; ++c) {
        eA[c] = __expf(acc[nt][gb * 4 + c]     - dg[kt2 * 16 + 4 * lh + c]);
        eB[c] = __expf(acc[nt][gb * 4 + 4 + c] - dg[kt2 * 16 + 8 + 4 * lh + c]);
      }
      unsigned p00 = pk2(eA[0], eA[1]), p01 = pk2(eA[2], eA[3]);
      unsigned p10 = pk2(eB[0], eB[1]), p11 = pk2(eB[2], eB[3]);
      unsigned o10 = __shfl_xor(p10, 32), o00 = __shfl_xor(p00, 32);
      unsigned o11 = __shfl_xor(p11, 32), o01 = __shfl_xor(p01, 32);
      uint4 W;
      W.x = lh ? o10 : p00;
      W.y = lh ? o11 : p01;
      W.z = lh ? p10 : o00;
      W.w = lh ? p11 : o01;
      bf16x8 af = __builtin_bit_cast(bf16x8, W);
#pragma unroll
      for (int et = 0; et < 2; ++et) {
        const int e = 32 * et + l31;
        bf16x8 bv = *(const bf16x8*)(smc + VT + e * 128 + ((kt2 * 32 + 16 * lh) ^ swzV(e)));
        accS[et] = MFMA32(af, bv, accS[et]);
      }
    }
    __syncthreads();
    if (tile + 1 < ntiles) {
#pragma unroll
      for (int j = 0; j < 8; ++j) { kx[j] = kn[j]; vx[j] = vn[j]; }
    }
  }
  // ---- S1 partials ----
  {
    float* o = s1p + (size_t)bid * (MM * 64);
#pragma unroll
    for (int et = 0; et < 2; ++et)
#pragma unroll
      for (int i = 0; i < 16; ++i) {
        const int m = wv * 32 + 4 * lh + (i & 3) + 8 * (i >> 2);
        o[m * 64 + 32 * et + l31] = accS[et][i];
      }
  }
  // ---- S2 reduce via LDS scratch (reuse KH/KL after final barrier) ----
  {
    float* scr = (float*)smc; // [64 r][64 e]
    *(float4*)&scr[r * 64 + c0]     = make_float4(s2loc[0], s2loc[1], s2loc[2], s2loc[3]);
    *(float4*)&scr[r * 64 + c0 + 4] = make_float4(s2loc[4], s2loc[5], s2loc[6], s2loc[7]);
    __syncthreads();
    if (t < 64) {
      float s = 0.f;
      for (int rr = 0; rr < 64; ++rr) s += scr[rr * 64 + t];
      s2p[(size_t)bid * 64 + t] = s;
    }
  }
  // ---- global max ----
#pragma unroll
  for (int off = 32; off; off >>= 1) gmax = fmaxf(gmax, __shfl_xor(gmax, off));
  if (l == 0) ((float*)(smc + RD))[wv] = gmax;
  __syncthreads();
  if (t == 0) {
    const float* rd = (const float*)(smc + RD);
    float m8 = rd[0];
#pragma unroll
    for (int w = 1; w < 8; ++w) m8 = fmaxf(m8, rd[w]);
    unsigned b = __float_as_uint(m8);
    unsigned key = (b & 0x80000000u) ? ~b : (b | 0x80000000u);
    atomicMax(kmaxp, key);
  }
}

// ---------------- ctx_finalize (split 4-way per bh): ctx = ratio*(e^-stab*S1 + eps*S2);
//                  pack cb B-frags; write epst partials (deterministic, no atomics) ----------------
__global__ void ctx_finalize(const float* __restrict__ s1p, const float* __restrict__ s2p,
                             const unsigned* __restrict__ kmaxp, unsigned short* __restrict__ cbU,
                             float* __restrict__ epstP, int NC) {
  __shared__ float ctxl[64 * 64];
  __shared__ float s2s[64];
  __shared__ float csr[4 * 64];
  const int t = threadIdx.x;
  const int bh = blockIdx.x >> 2, g = blockIdx.x & 3;
  const unsigned key = *kmaxp;
  const unsigned b = (key & 0x80000000u) ? (key & 0x7fffffffu) : ~key;
  const float stab = __uint_as_float(b);
  const float esc = RATIO * __expf(-stab);
  if (t < 64) {
    float s = 0.f;
    for (int nc = 0; nc < NC; ++nc) s += s2p[(size_t)(bh * NC + nc) * 64 + t];
    s2s[t] = RATIO * EPSK * s;
  }
  __syncthreads();
  const int e = t & 63, w = t >> 6;
  float cs = 0.f;
  for (int i = 0; i < 16; ++i) {
    const int ml = i * 4 + w;               // local m within this g-slice
    const int idx = (g * 64 + ml) * 64 + e; // global (m, e)
    float s = 0.f;
    for (int nc = 0; nc < NC; ++nc) s += s1p[(size_t)(bh * NC + nc) * 16384 + idx];
    const float val = esc * s + s2s[e];
    ctxl[ml * 64 + e] = val;
    cs += val;
  }
  csr[w * 64 + e] = cs;
  __syncthreads();
  if (t < 64)
    epstP[(size_t)(bh * 4 + g) * 64 + t] =
        RATIO * EPSK * (csr[t] + csr[64 + t] + csr[128 + t] + csr[192 + t]);
  // pack cb B-frags for kt in [4g, 4g+4): lane l: col e=et*32+(l&31), k(m)=kt*16+8*(l>>5)+j
  const int l = t & 63;
  unsigned short* cbB = cbU + (size_t)bh * 16384;
  for (int it = 0; it < 2; ++it) {
    const int cl = it * 4 + w;     // 0..7
    const int ktl = cl >> 1, et = cl & 1;
    const int kt = g * 4 + ktl;
    unsigned short pk[8];
#pragma unroll
    for (int j = 0; j < 8; ++j) {
      const int ml = ktl * 16 + 8 * (l >> 5) + j;
      const int e2 = et * 32 + (l & 31);
      pk[j] = bfu(ctxl[ml * 64 + e2]);
    }
    uint4 u = make_uint4(pk[0] | ((unsigned)pk[1] << 16), pk[2] | ((unsigned)pk[3] << 16),
                         pk[4] | ((unsigned)pk[5] << 16), pk[6] | ((unsigned)pk[7] << 16));
    *(uint4*)(cbB + (size_t)((kt * 2 + et) * 64 + l) * 8) = u;
  }
}

// ---------------- q_pass: xd^T (A=proj rows m, B=Q cols n), per-row max, Eq -> LDS b64,
//                  out = ratio*Eq·cb + epst ----------------
__global__ __launch_bounds__(256, 3) void q_pass(
    const float* __restrict__ qq, const bf16x8* __restrict__ paG,
    const bf16x8* __restrict__ cbG, const float* __restrict__ epstP,
    float* __restrict__ outp, int NC2) {
  extern __shared__ char smc[];
  constexpr int QH = 0, QL = 8192, EQ = 16384, DG = 49152, WQ = 49408;
  const int t = threadIdx.x, l = t & 63, wv = t >> 6;
  const int l31 = l & 31, lh = l >> 5;
  const int bid = blockIdx.x, bh = bid / NC2, nc = bid - bh * NC2;
  const int rowsPB = NN / NC2, ntiles = rowsPB >> 6;
  const float* qb = qq + (size_t)bh * NN * DD;
  float* ob = outp + (size_t)bh * NN * DD;
  const int r = t >> 2, c0 = (t & 3) * 16;
  const int swr = (r & 7) << 4;
  const int pnt = wv & 1, pet = wv >> 1;
  const bf16x8* cbB = cbG + (size_t)bh * 2048;
  float ept = 0.f;
#pragma unroll
  for (int g = 0; g < 4; ++g) ept += epstP[(size_t)(bh * 4 + g) * 64 + pet * 32 + l31];

  // proj A-frags for this wave's m-range (persistent regs)
  bf16x8 paw[2][4];
#pragma unroll
  for (int mt2 = 0; mt2 < 2; ++mt2)
#pragma unroll
    for (int kt = 0; kt < 4; ++kt)
      paw[mt2][kt] = paG[((wv * 2 + mt2) * 4 + kt) * 64 + l];

  float qx[16];
  {
    const float* s = qb + (size_t)(nc * rowsPB + r) * DD + c0;
    *(float4*)&qx[0]  = *(const float4*)(s + 0);
    *(float4*)&qx[4]  = *(const float4*)(s + 4);
    *(float4*)&qx[8]  = *(const float4*)(s + 8);
    *(float4*)&qx[12] = *(const float4*)(s + 12);
  }

  for (int tile = 0; tile < ntiles; ++tile) {
    const int n0 = nc * rowsPB + (tile << 6);
    // ---- stage Q hi/lo + diag ----
    {
      uint4 H0, L0, H1, L1;
      pack_hilo8(qx, H0, L0);
      pack_hilo8(qx + 8, H1, L1);
      *(uint4*)(smc + QH + r * 128 + ((2 * c0) ^ swr))      = H0;
      *(uint4*)(smc + QH + r * 128 + ((2 * c0 + 16) ^ swr)) = H1;
      *(uint4*)(smc + QL + r * 128 + ((2 * c0) ^ swr))      = L0;
      *(uint4*)(smc + QL + r * 128 + ((2 * c0 + 16) ^ swr)) = L1;
      float ds = 0.f;
#pragma unroll
      for (int j = 0; j < 16; ++j) ds += qx[j] * qx[j];
      ds += __shfl_xor(ds, 1);
      ds += __shfl_xor(ds, 2);
      if ((t & 3) == 0) ((float*)(smc + DG))[r] = ds * 0.0625f;
    }
    __syncthreads();
    float qn[16];
    if (tile + 1 < ntiles) {
      const float* s = qb + (size_t)(n0 + 64 + r) * DD + c0;
      *(float4*)&qn[0]  = *(const float4*)(s + 0);
      *(float4*)&qn[4]  = *(const float4*)(s + 4);
      *(float4*)&qn[8]  = *(const float4*)(s + 8);
      *(float4*)&qn[12] = *(const float4*)(s + 12);
    }
    // ---- phase A ----
    f32x16 acc[2][2];
#pragma unroll
    for (int a = 0; a < 2; ++a)
#pragma unroll
      for (int b2 = 0; b2 < 2; ++b2)
#pragma unroll
        for (int i = 0; i < 16; ++i) acc[a][b2][i] = 0.f;
    const int swa = (l31 & 7) << 4;
#pragma unroll
    for (int kt = 0; kt < 4; ++kt) {
      const int ko = kt * 32 + 16 * lh;
      bf16x8 bh0 = *(const bf16x8*)(smc + QH + l31 * 128 + (ko ^ swa));
      bf16x8 bl0 = *(const bf16x8*)(smc + QL + l31 * 128 + (ko ^ swa));
      bf16x8 bh1 = *(const bf16x8*)(smc + QH + (32 + l31) * 128 + (ko ^ swa));
      bf16x8 bl1 = *(const bf16x8*)(smc + QL + (32 + l31) * 128 + (ko ^ swa));
      acc[0][0] = MFMA32(paw[0][kt], bh0, acc[0][0]); acc[0][0] = MFMA32(paw[0][kt], bl0, acc[0][0]);
      acc[0][1] = MFMA32(paw[0][kt], bh1, acc[0][1]); acc[0][1] = MFMA32(paw[0][kt], bl1, acc[0][1]);
      acc[1][0] = MFMA32(paw[1][kt], bh0, acc[1][0]); acc[1][0] = MFMA32(paw[1][kt], bl0, acc[1][0]);
      acc[1][1] = MFMA32(paw[1][kt], bh1, acc[1][1]); acc[1][1] = MFMA32(paw[1][kt], bl1, acc[1][1]);
    }
    // ---- per-row (per-n) max ----
    {
      float pm0 = -3.0e38f, pm1 = -3.0e38f;
#pragma unroll
      for (int mt2 = 0; mt2 < 2; ++mt2)
#pragma unroll
        for (int i = 0; i < 16; ++i) {
          pm0 = fmaxf(pm0, acc[mt2][0][i]);
          pm1 = fmaxf(pm1, acc[mt2][1][i]);
        }
      pm0 = fmaxf(pm0, __shfl_xor(pm0, 32));
      pm1 = fmaxf(pm1, __shfl_xor(pm1, 32));
      if (l < 32) {
        ((float*)(smc + WQ))[wv * 64 + l] = pm0;
        ((float*)(smc + WQ))[wv * 64 + 32 + l] = pm1;
      }
    }
    __syncthreads();
    {
      const float* wq = (const float*)(smc + WQ);
      const float rm0 = fmaxf(fmaxf(wq[l31], wq[64 + l31]), fmaxf(wq[128 + l31], wq[192 + l31]));
      const float rm1 = fmaxf(fmaxf(wq[32 + l31], wq[96 + l31]), fmaxf(wq[160 + l31], wq[224 + l31]));
      const float dv0 = ((const float*)(smc + DG))[l31] + rm0;
      const float dv1 = ((const float*)(smc + DG))[32 + l31] + rm1;
      // Eq -> LDS [n][m] bf16 (A-frag layout for PV), b64 packed writes
      const int swq = (l31 & 7) << 4;
#pragma unroll
      for (int mt2 = 0; mt2 < 2; ++mt2) {
        const int mb = (wv * 2 + mt2) * 32 + 4 * lh;
#pragma unroll
        for (int ig = 0; ig < 4; ++ig) {
          const int m0 = mb + 8 * ig;
          uint2 u, v2;
          u.x  = pk2(__expf(acc[mt2][0][ig * 4 + 0] - dv0), __expf(acc[mt2][0][ig * 4 + 1] - dv0));
          u.y  = pk2(__expf(acc[mt2][0][ig * 4 + 2] - dv0), __expf(acc[mt2][0][ig * 4 + 3] - dv0));
          v2.x = pk2(__expf(acc[mt2][1][ig * 4 + 0] - dv1), __expf(acc[mt2][1][ig * 4 + 1] - dv1));
          v2.y = pk2(__expf(acc[mt2][1][ig * 4 + 2] - dv1), __expf(acc[mt2][1][ig * 4 + 3] - dv1));
          *(uint2*)(smc + EQ + l31 * 512 + ((2 * m0) ^ swq)) = u;
          *(uint2*)(smc + EQ + (32 + l31) * 512 + ((2 * m0) ^ swq)) = v2;
        }
      }
    }
    __syncthreads();
    // ---- PV: out subtile (pnt, pet), K=256 over m, 2-acc ILP, 1-deep cb prefetch ----
    {
      f32x16 p0, p1;
#pragma unroll
      for (int i = 0; i < 16; ++i) { p0[i] = 0.f; p1[i] = 0.f; }
      const int n = pnt * 32 + l31;
      const int swn = (n & 7) << 4;
      bf16x8 bcur = cbB[(0 * 2 + pet) * 64 + l];
#pragma unroll
      for (int kt = 0; kt < 16; ++kt) {
        bf16x8 bnx = bcur;
        if (kt < 15) bnx = cbB[((kt + 1) * 2 + pet) * 64 + l];
        bf16x8 afq = *(const bf16x8*)(smc + EQ + n * 512 + ((kt * 32 + 16 * lh) ^ swn));
        if (kt & 1) p1 = MFMA32(afq, bcur, p1);
        else        p0 = MFMA32(afq, bcur, p0);
        bcur = bnx;
      }
#pragma unroll
      for (int i = 0; i < 16; ++i) {
        const int nn = pnt * 32 + 4 * lh + (i & 3) + 8 * (i >> 2);
        const int e = pet * 32 + l31;
        ob[(size_t)(n0 + nn) * 64 + e] = RATIO * (p0[i] + p1[i]) + ept;
      }
    }
    if (tile + 1 < ntiles) {
#pragma unroll
      for (int j = 0; j < 16; ++j) qx[j] = qn[j];
    }
  }
}

extern "C" void kernel_launch(void* const* d_in, const int* in_sizes, int n_in,
                              void* d_out, int out_size, void* d_ws, size_t ws_size,
                              hipStream_t stream) {
  (void)in_sizes; (void)n_in; (void)out_size;
  const float* q    = (const float*)d_in[0];
  const float* k    = (const float*)d_in[1];
  const float* v    = (const float*)d_in[2];
  const float* proj = (const float*)d_in[3];
  float* out = (float*)d_out;
  char* wsb = (char*)d_ws;

  int NC = 8;
  auto need = [&](int nc) -> size_t {
    size_t off = 256 + 32768;                  // key + pa
    off += (size_t)nc * NBH * MM * 64 * 4;     // S1 partials
    off += (size_t)nc * NBH * 64 * 4;          // S2 partials
    off += (size_t)NBH * MM * 64 * 2;          // cb (bf16)
    off += (size_t)NBH * 4 * 64 * 4;           // epst partials
    return off;
  };
  while (NC > 1 && need(NC) > ws_size) NC >>= 1;

  unsigned* kmaxp = (unsigned*)wsb;
  bf16x8* paG = (bf16x8*)(wsb + 256);
  float* s1p = (float*)(wsb + 256 + 32768);
  float* s2p = (float*)((char*)s1p + (size_t)NC * NBH * MM * 64 * 4);
  unsigned short* cbU = (unsigned short*)((char*)s2p + (size_t)NC * NBH * 64 * 4);
  float* epstP = (float*)((char*)cbU + (size_t)NBH * MM * 64 * 2);
  const int NC2 = 32;

  const size_t lds_k = 24864, lds_q = 50432;
  hipFuncSetAttribute((const void*)k_pass, hipFuncAttributeMaxDynamicSharedMemorySize, (int)lds_k);
  hipFuncSetAttribute((const void*)q_pass, hipFuncAttributeMaxDynamicSharedMemorySize, (int)lds_q);

  hipMemsetAsync(wsb, 0, 4, stream); // kmax key = 0 (== -inf under monotone map)
  hipLaunchKernelGGL(prep_proj, dim3(32), dim3(64), 0, stream, proj, (unsigned short*)paG);
  hipLaunchKernelGGL(k_pass, dim3(NBH * NC), dim3(512), lds_k, stream, k, v, paG, s1p, s2p, kmaxp, NC);
  hipLaunchKernelGGL(ctx_finalize, dim3(NBH * 4), dim3(256), 0, stream, s1p, s2p, kmaxp, cbU, epstP, NC);
  hipLaunchKernelGGL(q_pass, dim3(NBH * NC2), dim3(256), lds_q, stream, q, paG, (const bf16x8*)cbU, epstP, out, NC2);
}

// Round 4
// 210.647 us; speedup vs baseline: 4.7660x; 1.4178x over previous
//
#include <hip/hip_runtime.h>
#include <cstdint>

typedef __bf16 bf16x8 __attribute__((ext_vector_type(8)));
typedef float f32x16 __attribute__((ext_vector_type(16)));

#define MFMA32(a, b, c) __builtin_amdgcn_mfma_f32_32x32x16_bf16(a, b, c, 0, 0, 0)

static constexpr int NBH = 64;     // B*H
static constexpr int NN  = 4096;
static constexpr int DD  = 64;
static constexpr int MM  = 256;
static constexpr float DATA_NORM = 0.35355339059327373f; // 64^-0.25
static constexpr float RATIO     = 0.0625f;              // 1/sqrt(256)
static constexpr float EPSK      = 1e-4f;

__device__ __forceinline__ unsigned short bfu(float f) {
  return __builtin_bit_cast(unsigned short, (__bf16)f);
}
__device__ __forceinline__ unsigned pk2(float a, float b) {
  return (unsigned)bfu(a) | ((unsigned)bfu(b) << 16);
}
// hi/lo split-pack of 8 floats -> two bf16x8 (hi, residual lo)
__device__ __forceinline__ void pack_hilo8(const float* x, bf16x8& H, bf16x8& L) {
  unsigned h[4], lo[4];
#pragma unroll
  for (int p = 0; p < 4; ++p) {
    float a = x[2 * p], b = x[2 * p + 1];
    __bf16 ha = (__bf16)a, hb = (__bf16)b;
    __bf16 la = (__bf16)(a - (float)ha), lb = (__bf16)(b - (float)hb);
    h[p]  = (unsigned)__builtin_bit_cast(unsigned short, ha) |
            ((unsigned)__builtin_bit_cast(unsigned short, hb) << 16);
    lo[p] = (unsigned)__builtin_bit_cast(unsigned short, la) |
            ((unsigned)__builtin_bit_cast(unsigned short, lb) << 16);
  }
  H = __builtin_bit_cast(bf16x8, make_uint4(h[0], h[1], h[2], h[3]));
  L = __builtin_bit_cast(bf16x8, make_uint4(lo[0], lo[1], lo[2], lo[3]));
}
// VT layout: [ncb:4][wrap(e):8][grp(e):8 x 16B], grp = (e&7)^(wrap&7); +2*(n&7) for element
__device__ __forceinline__ int vtByte(int ncb, int e) {
  const int wrap = e >> 3;
  const int grp = (e & 7) ^ (wrap & 7);
  return ncb * 1024 + wrap * 128 + grp * 16;
}

// ---------------- prep: frag-packed proj (layout serves as both A-frag and B-frag) ----------------
// combo = mt*4+kt: lane l holds m = mt*32+(l&31), d = kt*16 + 8*(l>>5) + j
__global__ void prep_proj(const float* __restrict__ proj, unsigned short* __restrict__ paU) {
  const int l = threadIdx.x, combo = blockIdx.x; // 32 blocks x 64 thr
  const int mt = combo >> 2, kt = combo & 3;
  const int m = mt * 32 + (l & 31);
  const int d0 = kt * 16 + 8 * (l >> 5);
  unsigned short pk[8];
#pragma unroll
  for (int j = 0; j < 8; ++j) pk[j] = bfu(DATA_NORM * proj[m * 64 + d0 + j]);
  uint4 u = make_uint4(pk[0] | ((unsigned)pk[1] << 16), pk[2] | ((unsigned)pk[3] << 16),
                       pk[4] | ((unsigned)pk[5] << 16), pk[6] | ((unsigned)pk[7] << 16));
  *(uint4*)(paU + (size_t)(combo * 64 + l) * 8) = u;
}

// ---------------- k_pass v4: K in regs (A-frag direct load, hi/lo), V' = exp(-diag)*V in tiny
//                  swizzled LDS (dbuf, 1 barrier/tile), E in-register via half-swap, S1 += E^T*V' ----
__global__ __launch_bounds__(512, 2) void k_pass(
    const float* __restrict__ kk, const float* __restrict__ vv,
    const bf16x8* __restrict__ paG, float* __restrict__ s1p,
    float* __restrict__ s2p, unsigned* __restrict__ kmaxp, int NC) {
  __shared__ __align__(16) char smc[8192 + 64];
  const int t = threadIdx.x, l = t & 63, wv = t >> 6;
  const int l31 = l & 31, lh = l >> 5;
  const int bid = blockIdx.x, bh = bid / NC, nc = bid - bh * NC;
  const int rowsPB = NN / NC, ntiles = rowsPB >> 5;
  const float* kb = kk + (size_t)bh * NN * DD;
  const float* vb = vv + (size_t)bh * NN * DD;
  const int ns = t >> 4, se0 = (t & 15) * 4;  // stager: row ns (tile-local), e-chunk
  const int base0 = nc * rowsPB;

  bf16x8 pb[4];  // proj B-frags for wave's m-slice (m = wv*32 + l31)
#pragma unroll
  for (int kt = 0; kt < 4; ++kt) pb[kt] = paG[(wv * 4 + kt) * 64 + l];

  f32x16 accS[2];
#pragma unroll
  for (int et = 0; et < 2; ++et)
#pragma unroll
    for (int i = 0; i < 16; ++i) accS[et][i] = 0.f;
  float s2loc[4] = {0.f, 0.f, 0.f, 0.f};
  float gmax = -3.0e38f;

  // prologue loads (tile 0): K A-frag rows (lane l31) + stager K/V rows
  float rk[32];
  float4 kv4, vv4;
#pragma unroll
  for (int kt = 0; kt < 4; ++kt) {
    const float* p = kb + (size_t)(base0 + l31) * DD + kt * 16 + 8 * lh;
    *(float4*)&rk[kt * 8]     = *(const float4*)p;
    *(float4*)&rk[kt * 8 + 4] = *(const float4*)(p + 4);
  }
  kv4 = *(const float4*)(kb + (size_t)(base0 + ns) * DD + se0);
  vv4 = *(const float4*)(vb + (size_t)(base0 + ns) * DD + se0);

  for (int tile = 0; tile < ntiles; ++tile) {
    char* vtc = smc + (tile & 1) * 4096;
    // ---- convert K to hi/lo frags ----
    bf16x8 KH[4], KL[4];
#pragma unroll
    for (int kt = 0; kt < 4; ++kt) pack_hilo8(&rk[kt * 8], KH[kt], KL[kt]);
    // ---- diag -> g, stage V' = g*V (bf16, swizzled), s2 partial ----
    {
      float ds = kv4.x * kv4.x + kv4.y * kv4.y + kv4.z * kv4.z + kv4.w * kv4.w;
      ds += __shfl_xor(ds, 1);
      ds += __shfl_xor(ds, 2);
      ds += __shfl_xor(ds, 4);
      ds += __shfl_xor(ds, 8);                     // 16-lane group shares row ns
      const float g = __expf(ds * -0.0625f);       // exp(-0.5*dn^2*|x|^2)
      const float vj[4] = {vv4.x, vv4.y, vv4.z, vv4.w};
      const int ncb = ns >> 3, np2 = (ns & 7) * 2;
#pragma unroll
      for (int j = 0; j < 4; ++j) {
        s2loc[j] += vj[j];
        *(unsigned short*)(vtc + vtByte(ncb, se0 + j) + np2) = bfu(vj[j] * g);
      }
    }
    // ---- issue next-tile loads (overlap with MFMA phase) ----
    float rkn[32];
    float4 kv4n, vv4n;
    if (tile + 1 < ntiles) {
      const int nb = base0 + (tile + 1) * 32;
#pragma unroll
      for (int kt = 0; kt < 4; ++kt) {
        const float* p = kb + (size_t)(nb + l31) * DD + kt * 16 + 8 * lh;
        *(float4*)&rkn[kt * 8]     = *(const float4*)p;
        *(float4*)&rkn[kt * 8 + 4] = *(const float4*)(p + 4);
      }
      kv4n = *(const float4*)(kb + (size_t)(nb + ns) * DD + se0);
      vv4n = *(const float4*)(vb + (size_t)(nb + ns) * DD + se0);
    }
    __syncthreads();
    // ---- phase A: xd (rows n in regs, cols m = lane) ----
    f32x16 acc;
#pragma unroll
    for (int i = 0; i < 16; ++i) acc[i] = 0.f;
#pragma unroll
    for (int kt = 0; kt < 4; ++kt) {
      acc = MFMA32(KH[kt], pb[kt], acc);
      acc = MFMA32(KL[kt], pb[kt], acc);
    }
#pragma unroll
    for (int i = 0; i < 16; ++i) gmax = fmaxf(gmax, acc[i]);
    // ---- per 16-n chunk: E = exp(xd), pack, half-swap -> A-frag, PV ----
#pragma unroll
    for (int kc = 0; kc < 2; ++kc) {
      float eA[4], eB[4];
#pragma unroll
      for (int c = 0; c < 4; ++c) {
        eA[c] = __expf(acc[kc * 8 + c]);
        eB[c] = __expf(acc[kc * 8 + 4 + c]);
      }
      unsigned p00 = pk2(eA[0], eA[1]), p01 = pk2(eA[2], eA[3]);
      unsigned p10 = pk2(eB[0], eB[1]), p11 = pk2(eB[2], eB[3]);
      unsigned o00 = __shfl_xor(p00, 32), o01 = __shfl_xor(p01, 32);
      unsigned o10 = __shfl_xor(p10, 32), o11 = __shfl_xor(p11, 32);
      uint4 W;
      W.x = lh ? o10 : p00;
      W.y = lh ? o11 : p01;
      W.z = lh ? p10 : o00;
      W.w = lh ? p11 : o01;
      bf16x8 af = __builtin_bit_cast(bf16x8, W);
#pragma unroll
      for (int et = 0; et < 2; ++et) {
        const int e = et * 32 + l31;
        bf16x8 bv = *(const bf16x8*)(vtc + vtByte(kc * 2 + lh, e));
        accS[et] = MFMA32(af, bv, accS[et]);
      }
    }
    if (tile + 1 < ntiles) {
#pragma unroll
      for (int j = 0; j < 32; ++j) rk[j] = rkn[j];
      kv4 = kv4n;
      vv4 = vv4n;
    }
  }
  // ---- S1 partials ----
  {
    float* o = s1p + (size_t)bid * (MM * 64);
#pragma unroll
    for (int et = 0; et < 2; ++et)
#pragma unroll
      for (int i = 0; i < 16; ++i) {
        const int m = wv * 32 + 4 * lh + (i & 3) + 8 * (i >> 2);
        o[m * 64 + et * 32 + l31] = accS[et][i];
      }
  }
  __syncthreads();
  // ---- S2 reduce (reuse VT as scratch) + gmax ----
  {
    float* scr = (float*)smc;
    *(float4*)&scr[t * 4] = make_float4(s2loc[0], s2loc[1], s2loc[2], s2loc[3]);
#pragma unroll
    for (int off = 32; off; off >>= 1) gmax = fmaxf(gmax, __shfl_xor(gmax, off));
    if (l == 0) ((float*)(smc + 8192))[wv] = gmax;
    __syncthreads();
    if (t < 64) {
      float s = 0.f;
      for (int nn2 = 0; nn2 < 32; ++nn2) s += scr[(nn2 * 16 + (t >> 2)) * 4 + (t & 3)];
      s2p[(size_t)bid * 64 + t] = s;
    }
    if (t == 0) {
      const float* rd = (const float*)(smc + 8192);
      float m8 = rd[0];
#pragma unroll
      for (int w = 1; w < 8; ++w) m8 = fmaxf(m8, rd[w]);
      unsigned b = __float_as_uint(m8);
      unsigned key = (b & 0x80000000u) ? ~b : (b | 0x80000000u);
      atomicMax(kmaxp, key);
    }
  }
}

// ---------------- ctx_finalize (split 4-way per bh): ctx = ratio*(e^-stab*S1 + eps*S2);
//                  pack cb B-frags; write epst partials ----------------
__global__ void ctx_finalize(const float* __restrict__ s1p, const float* __restrict__ s2p,
                             const unsigned* __restrict__ kmaxp, unsigned short* __restrict__ cbU,
                             float* __restrict__ epstP, int NC) {
  __shared__ float ctxl[64 * 64];
  __shared__ float s2s[64];
  __shared__ float csr[4 * 64];
  const int t = threadIdx.x;
  const int bh = blockIdx.x >> 2, g = blockIdx.x & 3;
  const unsigned key = *kmaxp;
  const unsigned b = (key & 0x80000000u) ? (key & 0x7fffffffu) : ~key;
  const float stab = __uint_as_float(b);
  const float esc = RATIO * __expf(-stab);
  if (t < 64) {
    float s = 0.f;
    for (int nc = 0; nc < NC; ++nc) s += s2p[(size_t)(bh * NC + nc) * 64 + t];
    s2s[t] = RATIO * EPSK * s;
  }
  __syncthreads();
  const int e = t & 63, w = t >> 6;
  float cs = 0.f;
  for (int i = 0; i < 16; ++i) {
    const int ml = i * 4 + w;               // local m within this g-slice
    const int idx = (g * 64 + ml) * 64 + e; // global (m, e)
    float s = 0.f;
    for (int nc = 0; nc < NC; ++nc) s += s1p[(size_t)(bh * NC + nc) * 16384 + idx];
    const float val = esc * s + s2s[e];
    ctxl[ml * 64 + e] = val;
    cs += val;
  }
  csr[w * 64 + e] = cs;
  __syncthreads();
  if (t < 64)
    epstP[(size_t)(bh * 4 + g) * 64 + t] =
        RATIO * EPSK * (csr[t] + csr[64 + t] + csr[128 + t] + csr[192 + t]);
  // pack cb B-frags for kt in [4g, 4g+4): lane l: col e=et*32+(l&31), k(m)=kt*16+8*(l>>5)+j
  const int l = t & 63;
  unsigned short* cbB = cbU + (size_t)bh * 16384;
  for (int it = 0; it < 2; ++it) {
    const int cl = it * 4 + w;     // 0..7
    const int ktl = cl >> 1, et = cl & 1;
    const int kt = g * 4 + ktl;
    unsigned short pk[8];
#pragma unroll
    for (int j = 0; j < 8; ++j) {
      const int ml = ktl * 16 + 8 * (l >> 5) + j;
      const int e2 = et * 32 + (l & 31);
      pk[j] = bfu(ctxl[ml * 64 + e2]);
    }
    uint4 u = make_uint4(pk[0] | ((unsigned)pk[1] << 16), pk[2] | ((unsigned)pk[3] << 16),
                         pk[4] | ((unsigned)pk[5] << 16), pk[6] | ((unsigned)pk[7] << 16));
    *(uint4*)(cbB + (size_t)((kt * 2 + et) * 64 + l) * 8) = u;
  }
}

// ---------------- q_pass v4: zero-LDS, zero-barrier. Wave owns 32 rows x all m.
//                  A=proj, B=Q(hi/lo) -> n in lane: diag/rmax in-lane. Two-pass, then PV. ----------
__global__ __launch_bounds__(256, 3) void q_pass(
    const float* __restrict__ qq, const bf16x8* __restrict__ paG,
    const bf16x8* __restrict__ cbG, const float* __restrict__ epstP,
    float* __restrict__ outp) {
  const int t = threadIdx.x, l = t & 63, wv = t >> 6;
  const int l31 = l & 31, lh = l >> 5;
  const int bid = blockIdx.x, bh = bid >> 5, nc = bid & 31;
  const float* qb = qq + (size_t)bh * NN * DD;
  float* ob = outp + (size_t)bh * NN * DD;
  const int base = nc * 128 + wv * 32;
  const bf16x8* cbB = cbG + (size_t)bh * 2048;

  // load own Q row (lane pair l31 / l31+32 split d-halves), convert hi/lo, diag
  bf16x8 QH[4], QL[4];
  float ds = 0.f;
#pragma unroll
  for (int kt = 0; kt < 4; ++kt) {
    const float* p = qb + (size_t)(base + l31) * DD + kt * 16 + 8 * lh;
    float x[8];
    *(float4*)&x[0] = *(const float4*)p;
    *(float4*)&x[4] = *(const float4*)(p + 4);
#pragma unroll
    for (int j = 0; j < 8; ++j) ds += x[j] * x[j];
    pack_hilo8(x, QH[kt], QL[kt]);
  }
  ds += __shfl_xor(ds, 32);
  const float diag = ds * 0.0625f;

  // pass 1: row max (per lane = per n)
  float rmax = -3.0e38f;
  for (int mt = 0; mt < 8; ++mt) {
    bf16x8 pa[4];
#pragma unroll
    for (int kt = 0; kt < 4; ++kt) pa[kt] = paG[(mt * 4 + kt) * 64 + l];
    f32x16 acc;
#pragma unroll
    for (int i = 0; i < 16; ++i) acc[i] = 0.f;
#pragma unroll
    for (int kt = 0; kt < 4; ++kt) {
      acc = MFMA32(pa[kt], QH[kt], acc);
      acc = MFMA32(pa[kt], QL[kt], acc);
    }
#pragma unroll
    for (int i = 0; i < 16; ++i) rmax = fmaxf(rmax, acc[i]);
  }
  rmax = fmaxf(rmax, __shfl_xor(rmax, 32));
  const float dgr = diag + rmax;

  // pass 2: Eq = exp(xd - diag - rmax), half-swap -> A-frag, PV with cb
  f32x16 out0, out1;
#pragma unroll
  for (int i = 0; i < 16; ++i) { out0[i] = 0.f; out1[i] = 0.f; }
  for (int mt = 0; mt < 8; ++mt) {
    bf16x8 pa[4];
#pragma unroll
    for (int kt = 0; kt < 4; ++kt) pa[kt] = paG[(mt * 4 + kt) * 64 + l];
    f32x16 acc;
#pragma unroll
    for (int i = 0; i < 16; ++i) acc[i] = 0.f;
#pragma unroll
    for (int kt = 0; kt < 4; ++kt) {
      acc = MFMA32(pa[kt], QH[kt], acc);
      acc = MFMA32(pa[kt], QL[kt], acc);
    }
#pragma unroll
    for (int kc = 0; kc < 2; ++kc) {
      float eA[4], eB[4];
#pragma unroll
      for (int c = 0; c < 4; ++c) {
        eA[c] = __expf(acc[kc * 8 + c] - dgr);
        eB[c] = __expf(acc[kc * 8 + 4 + c] - dgr);
      }
      unsigned p00 = pk2(eA[0], eA[1]), p01 = pk2(eA[2], eA[3]);
      unsigned p10 = pk2(eB[0], eB[1]), p11 = pk2(eB[2], eB[3]);
      unsigned o00 = __shfl_xor(p00, 32), o01 = __shfl_xor(p01, 32);
      unsigned o10 = __shfl_xor(p10, 32), o11 = __shfl_xor(p11, 32);
      uint4 W;
      W.x = lh ? o10 : p00;
      W.y = lh ? o11 : p01;
      W.z = lh ? p10 : o00;
      W.w = lh ? p11 : o01;
      bf16x8 af = __builtin_bit_cast(bf16x8, W);
      const int ktc = mt * 2 + kc;
      out0 = MFMA32(af, cbB[(ktc * 2 + 0) * 64 + l], out0);
      out1 = MFMA32(af, cbB[(ktc * 2 + 1) * 64 + l], out1);
    }
  }
  float ept0 = 0.f, ept1 = 0.f;
#pragma unroll
  for (int g = 0; g < 4; ++g) {
    ept0 += epstP[(size_t)(bh * 4 + g) * 64 + l31];
    ept1 += epstP[(size_t)(bh * 4 + g) * 64 + 32 + l31];
  }
#pragma unroll
  for (int i = 0; i < 16; ++i) {
    const int row = base + 4 * lh + (i & 3) + 8 * (i >> 2);
    ob[(size_t)row * 64 + l31]      = RATIO * out0[i] + ept0;
    ob[(size_t)row * 64 + 32 + l31] = RATIO * out1[i] + ept1;
  }
}

extern "C" void kernel_launch(void* const* d_in, const int* in_sizes, int n_in,
                              void* d_out, int out_size, void* d_ws, size_t ws_size,
                              hipStream_t stream) {
  (void)in_sizes; (void)n_in; (void)out_size;
  const float* q    = (const float*)d_in[0];
  const float* k    = (const float*)d_in[1];
  const float* v    = (const float*)d_in[2];
  const float* proj = (const float*)d_in[3];
  float* out = (float*)d_out;
  char* wsb = (char*)d_ws;

  int NC = 8;
  auto need = [&](int nc) -> size_t {
    size_t off = 256 + 32768;                  // key + pa
    off += (size_t)nc * NBH * MM * 64 * 4;     // S1 partials
    off += (size_t)nc * NBH * 64 * 4;          // S2 partials
    off += (size_t)NBH * MM * 64 * 2;          // cb (bf16)
    off += (size_t)NBH * 4 * 64 * 4;           // epst partials
    return off;
  };
  while (NC > 1 && need(NC) > ws_size) NC >>= 1;

  unsigned* kmaxp = (unsigned*)wsb;
  bf16x8* paG = (bf16x8*)(wsb + 256);
  float* s1p = (float*)(wsb + 256 + 32768);
  float* s2p = (float*)((char*)s1p + (size_t)NC * NBH * MM * 64 * 4);
  unsigned short* cbU = (unsigned short*)((char*)s2p + (size_t)NC * NBH * 64 * 4);
  float* epstP = (float*)((char*)cbU + (size_t)NBH * MM * 64 * 2);

  hipMemsetAsync(wsb, 0, 4, stream); // kmax key = 0 (== -inf under monotone map)
  hipLaunchKernelGGL(prep_proj, dim3(32), dim3(64), 0, stream, proj, (unsigned short*)paG);
  hipLaunchKernelGGL(k_pass, dim3(NBH * NC), dim3(512), 0, stream, k, v, paG, s1p, s2p, kmaxp, NC);
  hipLaunchKernelGGL(ctx_finalize, dim3(NBH * 4), dim3(256), 0, stream, s1p, s2p, kmaxp, cbU, epstP, NC);
  hipLaunchKernelGGL(q_pass, dim3(NBH * 32), dim3(256), 0, stream, q, paG, (const bf16x8*)cbU, epstP, out);
}

// Round 6
// 200.357 us; speedup vs baseline: 5.0108x; 1.0514x over previous
//
#include <hip/hip_runtime.h>
#include <cstdint>

typedef __bf16 bf16x8 __attribute__((ext_vector_type(8)));
typedef float f32x16 __attribute__((ext_vector_type(16)));

#define MFMA32(a, b, c) __builtin_amdgcn_mfma_f32_32x32x16_bf16(a, b, c, 0, 0, 0)

static constexpr int NBH = 64;     // B*H
static constexpr int NN  = 4096;
static constexpr int DD  = 64;
static constexpr int MM  = 256;
static constexpr float DATA_NORM = 0.35355339059327373f; // 64^-0.25
static constexpr float RATIO     = 0.0625f;              // 1/sqrt(256)
static constexpr float EPSK      = 1e-4f;

__device__ __forceinline__ unsigned short bfu(float f) {
  return __builtin_bit_cast(unsigned short, (__bf16)f);
}
__device__ __forceinline__ unsigned pk2(float a, float b) {
  return (unsigned)bfu(a) | ((unsigned)bfu(b) << 16);
}
// truncation-split of 8 floats: hi = upper 16 bits (truncated), lo = RN(a - hi).
// a = hi + (a-hi) exactly; (a-hi) fits f32 exactly.
__device__ __forceinline__ void pack_hilo8(const float* x, bf16x8& H, bf16x8& L) {
  unsigned h[4], lo[4];
#pragma unroll
  for (int p = 0; p < 4; ++p) {
    const unsigned ua = __float_as_uint(x[2 * p]);
    const unsigned ub = __float_as_uint(x[2 * p + 1]);
    h[p] = (ua >> 16) | (ub & 0xFFFF0000u);
    const float ra = x[2 * p]     - __uint_as_float(ua & 0xFFFF0000u);
    const float rb = x[2 * p + 1] - __uint_as_float(ub & 0xFFFF0000u);
    lo[p] = pk2(ra, rb);
  }
  H = __builtin_bit_cast(bf16x8, make_uint4(h[0], h[1], h[2], h[3]));
  L = __builtin_bit_cast(bf16x8, make_uint4(lo[0], lo[1], lo[2], lo[3]));
}
// VT layout: [ncb:4][wrap(e):8][grp(e):8 x 16B], grp = (e&7)^(wrap&7); +2*(n&7) for element
__device__ __forceinline__ int vtByte(int ncb, int e) {
  const int wrap = e >> 3;
  const int grp = (e & 7) ^ (wrap & 7);
  return ncb * 1024 + wrap * 128 + grp * 16;
}

// ---------------- prep: frag-packed proj (layout serves as both A-frag and B-frag) ----------------
// combo = mt*4+kt: lane l holds m = mt*32+(l&31), d = kt*16 + 8*(l>>5) + j
__global__ void prep_proj(const float* __restrict__ proj, unsigned short* __restrict__ paU) {
  const int l = threadIdx.x, combo = blockIdx.x; // 32 blocks x 64 thr
  const int mt = combo >> 2, kt = combo & 3;
  const int m = mt * 32 + (l & 31);
  const int d0 = kt * 16 + 8 * (l >> 5);
  unsigned short pk[8];
#pragma unroll
  for (int j = 0; j < 8; ++j) pk[j] = bfu(DATA_NORM * proj[m * 64 + d0 + j]);
  uint4 u = make_uint4(pk[0] | ((unsigned)pk[1] << 16), pk[2] | ((unsigned)pk[3] << 16),
                       pk[4] | ((unsigned)pk[5] << 16), pk[6] | ((unsigned)pk[7] << 16));
  *(uint4*)(paU + (size_t)(combo * 64 + l) * 8) = u;
}

// ---------------- k_pass v5: pack -> stage -> barrier -> ISSUE LOADS -> compute.
//                  Prefetch overlaps the MFMA/exp/PV phase (no vmcnt drain at the barrier). ---------
__global__ __launch_bounds__(512, 2) void k_pass(
    const float* __restrict__ kk, const float* __restrict__ vv,
    const bf16x8* __restrict__ paG, float* __restrict__ s1p,
    float* __restrict__ s2p, unsigned* __restrict__ kmaxp, int NC) {
  __shared__ __align__(16) char smc[8192 + 64];
  const int t = threadIdx.x, l = t & 63, wv = t >> 6;
  const int l31 = l & 31, lh = l >> 5;
  const int bid = blockIdx.x, bh = bid / NC, nc = bid - bh * NC;
  const int rowsPB = NN / NC, ntiles = rowsPB >> 5;
  const float* kb = kk + (size_t)bh * NN * DD;
  const float* vb = vv + (size_t)bh * NN * DD;
  const int ns = t >> 4, se0 = (t & 15) * 4;  // stager: row ns (tile-local), e-chunk
  const int base0 = nc * rowsPB;

  bf16x8 pb[4];  // proj B-frags for wave's m-slice (m = wv*32 + l31)
#pragma unroll
  for (int kt = 0; kt < 4; ++kt) pb[kt] = paG[(wv * 4 + kt) * 64 + l];

  f32x16 accS[2];
#pragma unroll
  for (int et = 0; et < 2; ++et)
#pragma unroll
    for (int i = 0; i < 16; ++i) accS[et][i] = 0.f;
  float s2loc[4] = {0.f, 0.f, 0.f, 0.f};
  float gmax = -3.0e38f;

  // prologue loads (tile 0)
  float rk[32];
  float4 kv4, vv4;
#pragma unroll
  for (int kt = 0; kt < 4; ++kt) {
    const float* p = kb + (size_t)(base0 + l31) * DD + kt * 16 + 8 * lh;
    *(float4*)&rk[kt * 8]     = *(const float4*)p;
    *(float4*)&rk[kt * 8 + 4] = *(const float4*)(p + 4);
  }
  kv4 = *(const float4*)(kb + (size_t)(base0 + ns) * DD + se0);
  vv4 = *(const float4*)(vb + (size_t)(base0 + ns) * DD + se0);

  for (int tile = 0; tile < ntiles; ++tile) {
    char* vtc = smc + (tile & 1) * 4096;
    // ---- convert K to hi/lo frags (consumes rk before it is overwritten) ----
    bf16x8 KH[4], KL[4];
#pragma unroll
    for (int kt = 0; kt < 4; ++kt) pack_hilo8(&rk[kt * 8], KH[kt], KL[kt]);
    // ---- diag -> g, stage V' = g*V (bf16, swizzled), s2 partial ----
    {
      float ds = kv4.x * kv4.x + kv4.y * kv4.y + kv4.z * kv4.z + kv4.w * kv4.w;
      ds += __shfl_xor(ds, 1);
      ds += __shfl_xor(ds, 2);
      ds += __shfl_xor(ds, 4);
      ds += __shfl_xor(ds, 8);                     // 16-lane group shares row ns
      const float g = __expf(ds * -0.0625f);       // exp(-0.5*dn^2*|x|^2)
      const float vj[4] = {vv4.x, vv4.y, vv4.z, vv4.w};
      const int ncb = ns >> 3, np2 = (ns & 7) * 2;
#pragma unroll
      for (int j = 0; j < 4; ++j) {
        s2loc[j] += vj[j];
        *(unsigned short*)(vtc + vtByte(ncb, se0 + j) + np2) = bfu(vj[j] * g);
      }
    }
    __syncthreads();
    // ---- NOW issue next-tile loads: they stay in flight across the whole compute phase ----
    if (tile + 1 < ntiles) {
      const int nb = base0 + (tile + 1) * 32;
#pragma unroll
      for (int kt = 0; kt < 4; ++kt) {
        const float* p = kb + (size_t)(nb + l31) * DD + kt * 16 + 8 * lh;
        *(float4*)&rk[kt * 8]     = *(const float4*)p;
        *(float4*)&rk[kt * 8 + 4] = *(const float4*)(p + 4);
      }
      kv4 = *(const float4*)(kb + (size_t)(nb + ns) * DD + se0);
      vv4 = *(const float4*)(vb + (size_t)(nb + ns) * DD + se0);
    }
    // ---- phase A: xd (rows n in regs, cols m = lane) ----
    f32x16 acc;
#pragma unroll
    for (int i = 0; i < 16; ++i) acc[i] = 0.f;
#pragma unroll
    for (int kt = 0; kt < 4; ++kt) {
      acc = MFMA32(KH[kt], pb[kt], acc);
      acc = MFMA32(KL[kt], pb[kt], acc);
    }
#pragma unroll
    for (int i = 0; i < 16; ++i) gmax = fmaxf(gmax, acc[i]);
    // ---- per 16-n chunk: E = exp(xd), pack, half-swap -> A-frag, PV ----
#pragma unroll
    for (int kc = 0; kc < 2; ++kc) {
      float eA[4], eB[4];
#pragma unroll
      for (int c = 0; c < 4; ++c) {
        eA[c] = __expf(acc[kc * 8 + c]);
        eB[c] = __expf(acc[kc * 8 + 4 + c]);
      }
      unsigned p00 = pk2(eA[0], eA[1]), p01 = pk2(eA[2], eA[3]);
      unsigned p10 = pk2(eB[0], eB[1]), p11 = pk2(eB[2], eB[3]);
      unsigned o00 = __shfl_xor(p00, 32), o01 = __shfl_xor(p01, 32);
      unsigned o10 = __shfl_xor(p10, 32), o11 = __shfl_xor(p11, 32);
      uint4 W;
      W.x = lh ? o10 : p00;
      W.y = lh ? o11 : p01;
      W.z = lh ? p10 : o00;
      W.w = lh ? p11 : o01;
      bf16x8 af = __builtin_bit_cast(bf16x8, W);
#pragma unroll
      for (int et = 0; et < 2; ++et) {
        const int e = et * 32 + l31;
        bf16x8 bv = *(const bf16x8*)(vtc + vtByte(kc * 2 + lh, e));
        accS[et] = MFMA32(af, bv, accS[et]);
      }
    }
  }
  // ---- S1 partials ----
  {
    float* o = s1p + (size_t)bid * (MM * 64);
#pragma unroll
    for (int et = 0; et < 2; ++et)
#pragma unroll
      for (int i = 0; i < 16; ++i) {
        const int m = wv * 32 + 4 * lh + (i & 3) + 8 * (i >> 2);
        o[m * 64 + et * 32 + l31] = accS[et][i];
      }
  }
  __syncthreads();
  // ---- S2 reduce (reuse VT as scratch) + gmax ----
  {
    float* scr = (float*)smc;
    *(float4*)&scr[t * 4] = make_float4(s2loc[0], s2loc[1], s2loc[2], s2loc[3]);
#pragma unroll
    for (int off = 32; off; off >>= 1) gmax = fmaxf(gmax, __shfl_xor(gmax, off));
    if (l == 0) ((float*)(smc + 8192))[wv] = gmax;
    __syncthreads();
    if (t < 64) {
      float s = 0.f;
      for (int nn2 = 0; nn2 < 32; ++nn2) s += scr[(nn2 * 16 + (t >> 2)) * 4 + (t & 3)];
      s2p[(size_t)bid * 64 + t] = s;
    }
    if (t == 0) {
      const float* rd = (const float*)(smc + 8192);
      float m8 = rd[0];
#pragma unroll
      for (int w = 1; w < 8; ++w) m8 = fmaxf(m8, rd[w]);
      unsigned b = __float_as_uint(m8);
      unsigned key = (b & 0x80000000u) ? ~b : (b | 0x80000000u);
      atomicMax(kmaxp, key);
    }
  }
}

// ---------------- ctx_finalize (split 4-way per bh): ctx = ratio*(e^-stab*S1 + eps*S2);
//                  pack cb B-frags; write epst partials ----------------
__global__ void ctx_finalize(const float* __restrict__ s1p, const float* __restrict__ s2p,
                             const unsigned* __restrict__ kmaxp, unsigned short* __restrict__ cbU,
                             float* __restrict__ epstP, int NC) {
  __shared__ float ctxl[64 * 64];
  __shared__ float s2s[64];
  __shared__ float csr[4 * 64];
  const int t = threadIdx.x;
  const int bh = blockIdx.x >> 2, g = blockIdx.x & 3;
  const unsigned key = *kmaxp;
  const unsigned b = (key & 0x80000000u) ? (key & 0x7fffffffu) : ~key;
  const float stab = __uint_as_float(b);
  const float esc = RATIO * __expf(-stab);
  if (t < 64) {
    float s = 0.f;
    for (int nc = 0; nc < NC; ++nc) s += s2p[(size_t)(bh * NC + nc) * 64 + t];
    s2s[t] = RATIO * EPSK * s;
  }
  __syncthreads();
  const int e = t & 63, w = t >> 6;
  float cs = 0.f;
  for (int i = 0; i < 16; ++i) {
    const int ml = i * 4 + w;               // local m within this g-slice
    const int idx = (g * 64 + ml) * 64 + e; // global (m, e)
    float s = 0.f;
    for (int nc = 0; nc < NC; ++nc) s += s1p[(size_t)(bh * NC + nc) * 16384 + idx];
    const float val = esc * s + s2s[e];
    ctxl[ml * 64 + e] = val;
    cs += val;
  }
  csr[w * 64 + e] = cs;
  __syncthreads();
  if (t < 64)
    epstP[(size_t)(bh * 4 + g) * 64 + t] =
        RATIO * EPSK * (csr[t] + csr[64 + t] + csr[128 + t] + csr[192 + t]);
  // pack cb B-frags for kt in [4g, 4g+4): lane l: col e=et*32+(l&31), k(m)=kt*16+8*(l>>5)+j
  const int l = t & 63;
  unsigned short* cbB = cbU + (size_t)bh * 16384;
  for (int it = 0; it < 2; ++it) {
    const int cl = it * 4 + w;     // 0..7
    const int ktl = cl >> 1, et = cl & 1;
    const int kt = g * 4 + ktl;
    unsigned short pk[8];
#pragma unroll
    for (int j = 0; j < 8; ++j) {
      const int ml = ktl * 16 + 8 * (l >> 5) + j;
      const int e2 = et * 32 + (l & 31);
      pk[j] = bfu(ctxl[ml * 64 + e2]);
    }
    uint4 u = make_uint4(pk[0] | ((unsigned)pk[1] << 16), pk[2] | ((unsigned)pk[3] << 16),
                         pk[4] | ((unsigned)pk[5] << 16), pk[6] | ((unsigned)pk[7] << 16));
    *(uint4*)(cbB + (size_t)((kt * 2 + et) * 64 + l) * 8) = u;
  }
}

// ---------------- q_pass v6: zero-LDS, zero-barrier, DEFERRED stabilization.
//                  U = sum_m exp(xd - diag) * ctx (unstabilized, bounded ~e^7 for Gaussian data);
//                  per-row stab applied ONCE at the end: out = ratio*exp(-stab_row)*U + epst. -------
__global__ __launch_bounds__(256, 3) void q_pass(
    const float* __restrict__ qq, const bf16x8* __restrict__ paG,
    const bf16x8* __restrict__ cbG, const float* __restrict__ epstP,
    float* __restrict__ outp) {
  const int t = threadIdx.x, l = t & 63, wv = t >> 6;
  const int l31 = l & 31, lh = l >> 5;
  const int bid = blockIdx.x, bh = bid >> 5, nc = bid & 31;
  const float* qb = qq + (size_t)bh * NN * DD;
  float* ob = outp + (size_t)bh * NN * DD;
  const int base = nc * 128 + wv * 32;
  const bf16x8* cbB = cbG + (size_t)bh * 2048;

  // load own Q row (lane pair l31 / l31+32 split d-halves), trunc-split, diag
  bf16x8 QH[4], QL[4];
  float ds = 0.f;
#pragma unroll
  for (int kt = 0; kt < 4; ++kt) {
    const float* p = qb + (size_t)(base + l31) * DD + kt * 16 + 8 * lh;
    float x[8];
    *(float4*)&x[0] = *(const float4*)p;
    *(float4*)&x[4] = *(const float4*)(p + 4);
#pragma unroll
    for (int j = 0; j < 8; ++j) ds += x[j] * x[j];
    pack_hilo8(x, QH[kt], QL[kt]);
  }
  ds += __shfl_xor(ds, 32);
  const float diag = ds * 0.0625f;

  f32x16 out0, out1;
#pragma unroll
  for (int i = 0; i < 16; ++i) { out0[i] = 0.f; out1[i] = 0.f; }
  float lmax = -3.0e38f;   // per-lane partial max over m of xd (col n = l31)

  bf16x8 pa[4];
#pragma unroll
  for (int kt = 0; kt < 4; ++kt) pa[kt] = paG[kt * 64 + l];

  for (int mt = 0; mt < 8; ++mt) {
    // phase A for this 32-m block: acc = xd, col n = l31, rows m in regs
    f32x16 acc;
#pragma unroll
    for (int i = 0; i < 16; ++i) acc[i] = 0.f;
#pragma unroll
    for (int kt = 0; kt < 4; ++kt) {
      acc = MFMA32(pa[kt], QH[kt], acc);
      acc = MFMA32(pa[kt], QL[kt], acc);
    }
    // prefetch cb for this mt's PV and pa for next mt (overlap the exp chain)
    bf16x8 cbv[4];
#pragma unroll
    for (int j = 0; j < 4; ++j) cbv[j] = cbB[(mt * 4 + j) * 64 + l];
    bf16x8 pan[4];
    if (mt < 7) {
#pragma unroll
      for (int kt = 0; kt < 4; ++kt) pan[kt] = paG[((mt + 1) * 4 + kt) * 64 + l];
    }
#pragma unroll
    for (int i = 0; i < 16; ++i) lmax = fmaxf(lmax, acc[i]);
    // Eq = exp(xd - diag) (unstabilized), half-swap -> A-frag, PV
#pragma unroll
    for (int kc = 0; kc < 2; ++kc) {
      float eA[4], eB[4];
#pragma unroll
      for (int c = 0; c < 4; ++c) {
        eA[c] = __expf(acc[kc * 8 + c] - diag);
        eB[c] = __expf(acc[kc * 8 + 4 + c] - diag);
      }
      unsigned p00 = pk2(eA[0], eA[1]), p01 = pk2(eA[2], eA[3]);
      unsigned p10 = pk2(eB[0], eB[1]), p11 = pk2(eB[2], eB[3]);
      unsigned o00 = __shfl_xor(p00, 32), o01 = __shfl_xor(p01, 32);
      unsigned o10 = __shfl_xor(p10, 32), o11 = __shfl_xor(p11, 32);
      uint4 W;
      W.x = lh ? o10 : p00;
      W.y = lh ? o11 : p01;
      W.z = lh ? p10 : o00;
      W.w = lh ? p11 : o01;
      bf16x8 af = __builtin_bit_cast(bf16x8, W);
      out0 = MFMA32(af, cbv[kc * 2 + 0], out0);
      out1 = MFMA32(af, cbv[kc * 2 + 1], out1);
    }
    if (mt < 7) {
#pragma unroll
      for (int kt = 0; kt < 4; ++kt) pa[kt] = pan[kt];
    }
  }
  // rmax for row l31 (combine the two d-half lanes of the QK^T layout)
  const float rmaxp = fmaxf(lmax, __shfl_xor(lmax, 32));
  float ept0 = 0.f, ept1 = 0.f;
#pragma unroll
  for (int g = 0; g < 4; ++g) {
    ept0 += epstP[(size_t)(bh * 4 + g) * 64 + l31];
    ept1 += epstP[(size_t)(bh * 4 + g) * 64 + 32 + l31];
  }
  // apply per-row stab exactly once: row rr's max lives in lane rr
#pragma unroll
  for (int i = 0; i < 16; ++i) {
    const int rr = 4 * lh + (i & 3) + 8 * (i >> 2);
    const float st = __shfl(rmaxp, rr);
    const float sc = RATIO * __expf(-st);
    const int row = base + rr;
    ob[(size_t)row * 64 + l31]      = sc * out0[i] + ept0;
    ob[(size_t)row * 64 + 32 + l31] = sc * out1[i] + ept1;
  }
}

extern "C" void kernel_launch(void* const* d_in, const int* in_sizes, int n_in,
                              void* d_out, int out_size, void* d_ws, size_t ws_size,
                              hipStream_t stream) {
  (void)in_sizes; (void)n_in; (void)out_size;
  const float* q    = (const float*)d_in[0];
  const float* k    = (const float*)d_in[1];
  const float* v    = (const float*)d_in[2];
  const float* proj = (const float*)d_in[3];
  float* out = (float*)d_out;
  char* wsb = (char*)d_ws;

  int NC = 8;
  auto need = [&](int nc) -> size_t {
    size_t off = 256 + 32768;                  // key + pa
    off += (size_t)nc * NBH * MM * 64 * 4;     // S1 partials
    off += (size_t)nc * NBH * 64 * 4;          // S2 partials
    off += (size_t)NBH * MM * 64 * 2;          // cb (bf16)
    off += (size_t)NBH * 4 * 64 * 4;           // epst partials
    return off;
  };
  while (NC > 1 && need(NC) > ws_size) NC >>= 1;

  unsigned* kmaxp = (unsigned*)wsb;
  bf16x8* paG = (bf16x8*)(wsb + 256);
  float* s1p = (float*)(wsb + 256 + 32768);
  float* s2p = (float*)((char*)s1p + (size_t)NC * NBH * MM * 64 * 4);
  unsigned short* cbU = (unsigned short*)((char*)s2p + (size_t)NC * NBH * 64 * 4);
  float* epstP = (float*)((char*)cbU + (size_t)NBH * MM * 64 * 2);

  hipMemsetAsync(wsb, 0, 4, stream); // kmax key = 0 (== -inf under monotone map)
  hipLaunchKernelGGL(prep_proj, dim3(32), dim3(64), 0, stream, proj, (unsigned short*)paG);
  hipLaunchKernelGGL(k_pass, dim3(NBH * NC), dim3(512), 0, stream, k, v, paG, s1p, s2p, kmaxp, NC);
  hipLaunchKernelGGL(ctx_finalize, dim3(NBH * 4), dim3(256), 0, stream, s1p, s2p, kmaxp, cbU, epstP, NC);
  hipLaunchKernelGGL(q_pass, dim3(NBH * 32), dim3(256), 0, stream, q, paG, (const bf16x8*)cbU, epstP, out);
}